// Round 26
// baseline (1359.927 us; speedup 1.0000x reference)
//
#include <hip/hip_runtime.h>
#include <hip/hip_bf16.h>

typedef __hip_bfloat16 bf16;
typedef unsigned short u16;
typedef __attribute__((ext_vector_type(8))) short short8v;  // 8 bf16 (4 VGPR)
typedef __attribute__((ext_vector_type(4))) float f32x4;

#define BB   4
#define CC_  256
#define HH   128
#define WW   128
#define HWn  16384
#define SZ   ((size_t)16777216)   // BB*CC_*HWn elements per slot

__device__ __forceinline__ float b2f(bf16 v){ return __bfloat162float(v); }
__device__ __forceinline__ bf16  f2b(float v){ return __float2bfloat16(v); }
__device__ __forceinline__ float us2f(u16 u){
  union { unsigned int i; float f; } x; x.i = ((unsigned int)u) << 16; return x.f;
}
__device__ __forceinline__ u16 f2us(float v){
  bf16 h = f2b(v); u16 u; __builtin_memcpy(&u, &h, 2); return u;
}
__device__ __forceinline__ void st4(float* p, float a, float b, float c, float d){
  *(float4*)p = make_float4(a,b,c,d);
}
__device__ __forceinline__ void st4(bf16* p, float a, float b, float c, float d){
  bf16 o[4] = { f2b(a), f2b(b), f2b(c), f2b(d) };
  *(uint2*)p = *(uint2*)o;
}
__device__ __forceinline__ void store1(float* p, float v){ *p = v; }
__device__ __forceinline__ void store1(bf16* p, float v){ *p = f2b(v); }

// Direct global->LDS 16B async load (per-lane global src, wave-uniform LDS
// base; lane i lands at base + i*16B).
typedef __attribute__((address_space(1))) const unsigned int u32g;
typedef __attribute__((address_space(3))) unsigned int u32l;
__device__ __forceinline__ void gl16(const void* g, void* l)
{
  u32g* gp = (u32g*)(unsigned long long)(size_t)g;
  u32l* lp = (u32l*)(unsigned int)(size_t)l;
  __builtin_amdgcn_global_load_lds(gp, lp, 16, 0, 0);
}

// ---------------------------------------------------------------------------
// Transpose [B,256,H,W] f32 -> [B,H,W,256] bf16. One block per (b,h).
// ---------------------------------------------------------------------------
__global__ __launch_bounds__(256)
void k_xpose(const float* __restrict__ x, bf16* __restrict__ xt)
{
  const int b = blockIdx.x >> 7, h = blockIdx.x & 127;
  __shared__ u16 L[64][132];
  const int tid = threadIdx.x;
  for (int c0 = 0; c0 < 256; c0 += 64) {
    for (int idx = tid; idx < 2048; idx += 256) {
      const int c = idx >> 5, w4 = (idx & 31) * 4;
      const float4 v = *(const float4*)&x[(((size_t)(b*CC_ + c0 + c))*HH + h)*WW + w4];
      L[c][w4]   = f2us(v.x); L[c][w4+1] = f2us(v.y);
      L[c][w4+2] = f2us(v.z); L[c][w4+3] = f2us(v.w);
    }
    __syncthreads();
    for (int idx = tid; idx < 1024; idx += 256) {
      const int w = idx >> 3, cg = (idx & 7) * 8;
      u16 tmp[8];
      #pragma unroll
      for (int j = 0; j < 8; ++j) tmp[j] = L[cg + j][w];
      *(uint4*)&xt[(((size_t)(b*HH + h))*WW + w)*256 + c0 + cg] = *(uint4*)tmp;
    }
    __syncthreads();
  }
}

// Fused GN-apply + transpose (branch 4): Tc16 [B,C,H,W] bf16 + stats ->
// xt [B,H,W,256] bf16.
__global__ __launch_bounds__(256)
void k_xpose_gn(const bf16* __restrict__ t, const float* __restrict__ stats,
                const float* __restrict__ sc, const float* __restrict__ bi,
                bf16* __restrict__ xt)
{
  const int b = blockIdx.x >> 7, h = blockIdx.x & 127;
  __shared__ u16 L[64][132];
  const int tid = threadIdx.x;
  const float cnt = 16.f * 16384.f;
  for (int c0 = 0; c0 < 256; c0 += 64) {
    for (int idx = tid; idx < 1024; idx += 256) {
      const int c = idx >> 4, w8 = (idx & 15) * 8;
      const int cg = c0 + c;
      const int bg = b*16 + (cg >> 4);
      const float mu  = stats[bg*2] / cnt;
      const float var = stats[bg*2+1] / cnt - mu * mu;
      const float a   = rsqrtf(var + 1e-5f) * sc[cg];
      const float bb  = bi[cg] - mu * a;
      u16 t8[8];
      *(uint4*)t8 = *(const uint4*)((const u16*)t + (((size_t)(b*CC_ + cg))*HH + h)*WW + w8);
      #pragma unroll
      for (int j = 0; j < 8; ++j) t8[j] = f2us(fmaxf(us2f(t8[j])*a + bb, 0.f));
      #pragma unroll
      for (int j = 0; j < 8; ++j) L[c][w8 + j] = t8[j];
    }
    __syncthreads();
    for (int idx = tid; idx < 1024; idx += 256) {
      const int w = idx >> 3, cg = (idx & 7) * 8;
      u16 tmp[8];
      #pragma unroll
      for (int j = 0; j < 8; ++j) tmp[j] = L[cg + j][w];
      *(uint4*)&xt[(((size_t)(b*HH + h))*WW + w)*256 + c0 + cg] = *(uint4*)tmp;
    }
    __syncthreads();
  }
}

// Inverse for branch-4 CC output: [B,H,W,256] bf16 -> [B,256,H,W] bf16,
// with fused CAM row-sumsq (32-lane-group reduce + 1 atomic per (b,c)).
__global__ __launch_bounds__(256)
void k_xposeb_b(const bf16* __restrict__ xt, bf16* __restrict__ fb,
                float* __restrict__ rownsq)
{
  const int b = blockIdx.x >> 7, h = blockIdx.x & 127;
  __shared__ u16 L[64][132];
  const int tid = threadIdx.x;
  for (int c0 = 0; c0 < 256; c0 += 64) {
    for (int idx = tid; idx < 1024; idx += 256) {
      const int w = idx >> 3, cg = (idx & 7) * 8;
      u16 t[8];
      *(uint4*)t = *(const uint4*)((const u16*)xt + (((size_t)(b*HH + h))*WW + w)*256 + c0 + cg);
      #pragma unroll
      for (int j = 0; j < 8; ++j) L[cg + j][w] = t[j];
    }
    __syncthreads();
    for (int idx = tid; idx < 2048; idx += 256) {
      const int c = idx >> 5, w4 = (idx & 31) * 4;
      u16 q[4] = { L[c][w4], L[c][w4+1], L[c][w4+2], L[c][w4+3] };
      *(uint2*)((u16*)fb + (((size_t)(b*CC_ + c0 + c))*HH + h)*WW + w4) = *(uint2*)q;
      float sq = 0.f;
      #pragma unroll
      for (int j = 0; j < 4; ++j) { const float v = us2f(q[j]); sq = fmaf(v, v, sq); }
      #pragma unroll
      for (int o = 16; o > 0; o >>= 1) sq += __shfl_xor(sq, o, 64);
      if ((tid & 31) == 0) atomicAdd(&rownsq[b*256 + c0 + c], sq);
    }
    __syncthreads();
  }
}

// Weights [CO,CI,taps] f32 -> wt [taps,CO,CI] bf16.
__global__ __launch_bounds__(256)
void k_wt(const float* __restrict__ w, bf16* __restrict__ wt, int taps)
{
  const int i = blockIdx.x * 256 + threadIdx.x;
  const int tap = i >> 16, r = i & 65535;
  const int co = r >> 8, ci = r & 255;
  if (tap < taps) wt[i] = f2b(w[(co*256 + ci)*taps + tap]);
}

// ---------------------------------------------------------------------------
// MFMA conv with global_load_lds staging (r21 proven). LDS linear [rows][32].
// STATS: fused GroupNorm stats (r23 proven).
// QKNORM (TRANS, CO==64, grid.x==1): fused per-pixel L2-normalize over the
// 64 output channels (replaces k_qknorm_t). Channels of a pixel live in the
// 4 lanes {lr+16*lg} x 16 regs; sumsq = lane-reduce + shfl_xor(16,32).
// ---------------------------------------------------------------------------
template<int KHW, typename DT, bool TRANS, bool STATS, bool QKNORM>
__global__ __launch_bounds__(256)
void k_convm(const bf16* __restrict__ xt, const bf16* __restrict__ wt,
             const float* __restrict__ bias, DT* __restrict__ dst, int dil, int CO,
             float* __restrict__ stats)
{
  const int b   = blockIdx.y >> 7;
  const int h   = blockIdx.y & 127;
  const int co0 = blockIdx.x * 64;
  const int tid = threadIdx.x;
  const int wid = tid >> 6;
  const int lane = tid & 63;
  const int lr = lane & 15;
  const int lg = lane >> 4;
  const int lrow = lane >> 2;        // row within 16-row chunk
  const int lci  = (lane & 3) * 8;   // 16B slot (8 u16) within row

  __shared__ __align__(16) u16 Asld[KHW*64][32];
  __shared__ __align__(16) u16 Bsld[164][32];

  // Pre-zero the constant pad rows of B (0..17 and 146..163).
  for (int i = tid; i < 36*32; i += 256) {
    int r = i >> 5; r = (r < 18) ? r : (128 + r);
    Bsld[r][i & 31] = 0;
  }

  f32x4 acc[4][2] = {};

  for (int kh = 0; kh < KHW; ++kh) {
    const int hh = h + (kh - (KHW >> 1)) * dil;
    if (hh < 0 || hh >= HH) continue;
    const bf16* __restrict__ brow = xt + ((size_t)(b*HH + hh))*WW*256;
    for (int kc = 0; kc < 256; kc += 32) {
      for (int ch = wid; ch < KHW*4; ch += 4) {
        const int row = ch*16 + lrow;
        const int tap = row >> 6, cc = row & 63;
        gl16(wt + ((size_t)(kh*KHW + tap))*CO*256 + (co0 + cc)*256 + kc + lci,
             &Asld[ch*16][0]);
      }
      for (int ch = wid; ch < 8; ch += 4) {
        const int wpos = ch*16 + lrow;
        gl16(brow + (size_t)wpos*256 + kc + lci, &Bsld[18 + ch*16][0]);
      }
      __syncthreads();
      #pragma unroll
      for (int kw = 0; kw < KHW; ++kw) {
        const int pbase = 18 + (kw - (KHW >> 1)) * dil;
        short8v af[4], bfr[2];
        #pragma unroll
        for (int cf = 0; cf < 4; ++cf)
          af[cf] = *(const short8v*)&Asld[kw*64 + cf*16 + lr][lg*8];
        #pragma unroll
        for (int wf = 0; wf < 2; ++wf)
          bfr[wf] = *(const short8v*)&Bsld[pbase + wid*32 + wf*16 + lr][lg*8];
        #pragma unroll
        for (int cf = 0; cf < 4; ++cf)
          #pragma unroll
          for (int wf = 0; wf < 2; ++wf)
            acc[cf][wf] = __builtin_amdgcn_mfma_f32_16x16x32_bf16(
                            af[cf], bfr[wf], acc[cf][wf], 0, 0, 0);
      }
      __syncthreads();
    }
  }
  if constexpr (TRANS) {
    if constexpr (QKNORM) {
      // CO==64, co0==0. Fused per-pixel L2-norm over 64 channels.
      #pragma unroll
      for (int wf = 0; wf < 2; ++wf) {
        float vr[16];
        float sq = 0.f;
        #pragma unroll
        for (int cf = 0; cf < 4; ++cf)
          #pragma unroll
          for (int r = 0; r < 4; ++r) {
            const float v = us2f(f2us(acc[cf][wf][r] + bias[cf*16 + lg*4 + r]));
            vr[cf*4 + r] = v;
            sq = fmaf(v, v, sq);
          }
        sq += __shfl_xor(sq, 16, 64);
        sq += __shfl_xor(sq, 32, 64);
        const float rn = 1.f / (sqrtf(sq) + 1e-10f);
        const int wpix = wid*32 + wf*16 + lr;
        bf16* dr = (bf16*)dst + (((size_t)(b*HH + h))*WW + wpix)*CO + lg*4;
        #pragma unroll
        for (int cf = 0; cf < 4; ++cf) {
          bf16 o4[4];
          #pragma unroll
          for (int r = 0; r < 4; ++r) o4[r] = f2b(vr[cf*4 + r] * rn);
          *(uint2*)(dr + cf*16) = *(uint2*)o4;
        }
      }
    } else {
      #pragma unroll
      for (int cf = 0; cf < 4; ++cf) {
        float bb[4];
        #pragma unroll
        for (int r = 0; r < 4; ++r)
          bb[r] = bias ? bias[co0 + cf*16 + lg*4 + r] : 0.f;
        #pragma unroll
        for (int wf = 0; wf < 2; ++wf) {
          const int wpix = wid*32 + wf*16 + lr;
          bf16* dr = (bf16*)dst + (((size_t)(b*HH + h))*WW + wpix)*CO + co0 + cf*16 + lg*4;
          bf16 o4[4];
          #pragma unroll
          for (int r = 0; r < 4; ++r) o4[r] = f2b(acc[cf][wf][r] + bb[r]);
          *(uint2*)dr = *(uint2*)o4;
        }
      }
    }
  } else {
    float s0[4] = {0.f,0.f,0.f,0.f}, s1[4] = {0.f,0.f,0.f,0.f};
    #pragma unroll
    for (int cf = 0; cf < 4; ++cf) {
      #pragma unroll
      for (int r = 0; r < 4; ++r) {
        const int co = co0 + cf*16 + lg*4 + r;
        const float bb = bias ? bias[co] : 0.f;
        DT* drow = dst + (((size_t)(b*CO + co))*HH + h)*WW;
        #pragma unroll
        for (int wf = 0; wf < 2; ++wf) {
          const float v = acc[cf][wf][r] + bb;
          store1(drow + wid*32 + wf*16 + lr, v);
          if constexpr (STATS) {
            const float vr = us2f(f2us(v));   // rounded value, as stored
            s0[cf] += vr;
            s1[cf] = fmaf(vr, vr, s1[cf]);
          }
        }
      }
    }
    if constexpr (STATS) {
      #pragma unroll
      for (int cf = 0; cf < 4; ++cf)
        #pragma unroll
        for (int o = 32; o > 0; o >>= 1) {
          s0[cf] += __shfl_down(s0[cf], o, 64);
          s1[cf] += __shfl_down(s1[cf], o, 64);
        }
      __shared__ float sred[4][4][2];
      if (lane == 0) {
        #pragma unroll
        for (int cf = 0; cf < 4; ++cf) { sred[wid][cf][0] = s0[cf]; sred[wid][cf][1] = s1[cf]; }
      }
      __syncthreads();
      if (tid < 8) {
        const int cf = tid >> 1, j = tid & 1;
        const float t = sred[0][cf][j] + sred[1][cf][j] + sred[2][cf][j] + sred[3][cf][j];
        atomicAdd(&stats[(b*16 + (co0 >> 4) + cf)*2 + j], t);
      }
    }
  }
}

// GroupNorm apply -> bf16 (branches 0-3), fused CAM row-sumsq.
__global__ __launch_bounds__(256)
void k_gn_applyb(const bf16* __restrict__ t, const float* __restrict__ stats,
                 const float* __restrict__ sc, const float* __restrict__ bi,
                 bf16* __restrict__ dst, float* __restrict__ rownsq)
{
  const size_t e = ((size_t)blockIdx.x * 256 + threadIdx.x) * 4;
  const int c  = (int)((e >> 14) & 255);
  const int bg = (int)(e >> 22) * 16 + (c >> 4);
  const float cnt = 16.f * 16384.f;
  const float mu  = stats[bg*2] / cnt;
  const float var = stats[bg*2+1] / cnt - mu * mu;
  const float rs  = rsqrtf(var + 1e-5f);
  const float a   = rs * sc[c];
  const float bb  = bi[c] - mu * a;
  const ushort4 u = *(const ushort4*)((const u16*)t + e);
  u16 q[4] = { f2us(fmaxf(us2f(u.x)*a+bb,0.f)), f2us(fmaxf(us2f(u.y)*a+bb,0.f)),
               f2us(fmaxf(us2f(u.z)*a+bb,0.f)), f2us(fmaxf(us2f(u.w)*a+bb,0.f)) };
  *(uint2*)((u16*)dst + e) = *(uint2*)q;
  float sq = 0.f;
  #pragma unroll
  for (int j = 0; j < 4; ++j) { const float w = us2f(q[j]); sq = fmaf(w, w, sq); }
  #pragma unroll
  for (int o = 32; o > 0; o >>= 1) sq += __shfl_down(sq, o, 64);
  __shared__ float sh[4];
  const int wid = threadIdx.x >> 6, lane = threadIdx.x & 63;
  if (lane == 0) sh[wid] = sq;
  __syncthreads();
  if (threadIdx.x == 0) atomicAdd(&rownsq[blockIdx.x >> 4], sh[0]+sh[1]+sh[2]+sh[3]);
}

// ---------------------------------------------------------------------------
// MFMA energy: E[b] += F.F^T (bf16 copy of slot). Tile 128x128, split-K 32
// (k-chunk 512). gl16 staging into segmented LDS [2][128][32]. Full 4 tiles.
// ---------------------------------------------------------------------------
__global__ __launch_bounds__(256)
void k_energym(const bf16* __restrict__ fb, float* __restrict__ energy)
{
  const int b  = blockIdx.z;
  const int c0 = (blockIdx.x >> 1) * 128, d0 = (blockIdx.x & 1) * 128;
  const int k0 = blockIdx.y * 512;
  __shared__ __align__(16) u16 Au[2][128][32];
  __shared__ __align__(16) u16 Bu[2][128][32];
  const int tid = threadIdx.x;
  const int wid = tid >> 6, lane = tid & 63;
  const int lr = lane & 15, lg = lane >> 4;
  const int lrow = lane >> 2, lci = (lane & 3) * 8;
  const int row0w = (wid & 1) * 64, col0w = (wid >> 1) * 64;
  const u16* __restrict__ fbb = (const u16*)fb + (size_t)b * CC_ * HWn;

  f32x4 acc[4][4] = {};

  for (int kc = 0; kc < 512; kc += 64) {
    for (int ci = wid; ci < 16; ci += 4) {
      const int seg = ci >> 3, rq = (ci & 7) * 16;
      const int m = rq + lrow;
      gl16(fbb + (size_t)(c0 + m)*HWn + k0 + kc + seg*32 + lci, &Au[seg][rq][0]);
      gl16(fbb + (size_t)(d0 + m)*HWn + k0 + kc + seg*32 + lci, &Bu[seg][rq][0]);
    }
    __syncthreads();
    #pragma unroll
    for (int ks = 0; ks < 2; ++ks) {
      short8v af[4], bfv[4];
      #pragma unroll
      for (int cf = 0; cf < 4; ++cf)
        af[cf] = *(const short8v*)&Au[ks][row0w + cf*16 + lr][lg*8];
      #pragma unroll
      for (int df = 0; df < 4; ++df)
        bfv[df] = *(const short8v*)&Bu[ks][col0w + df*16 + lr][lg*8];
      #pragma unroll
      for (int cf = 0; cf < 4; ++cf)
        #pragma unroll
        for (int df = 0; df < 4; ++df)
          acc[cf][df] = __builtin_amdgcn_mfma_f32_16x16x32_bf16(
                          af[cf], bfv[df], acc[cf][df], 0, 0, 0);
    }
    __syncthreads();
  }
  #pragma unroll
  for (int cf = 0; cf < 4; ++cf)
    #pragma unroll
    for (int df = 0; df < 4; ++df)
      #pragma unroll
      for (int r = 0; r < 4; ++r) {
        const int row = c0 + row0w + cf*16 + lg*4 + r;
        const int col = d0 + col0w + df*16 + lr;
        atomicAdd(&energy[((size_t)(b*CC_ + row))*CC_ + col], acc[cf][df][r]);
      }
}

// ---------------------------------------------------------------------------
// MFMA camout: out = gamma*(att@f) + f. B and residual from bf16 copy.
// B staging: coalesced uint4 row reads + LDS transpose (outWm pattern; the
// old per-u16 scalar global reads were ~10x the transactions).
// ---------------------------------------------------------------------------
__global__ __launch_bounds__(512)
void k_camoutm(const float* __restrict__ catt, const bf16* __restrict__ fb,
               float* __restrict__ fio, const float* __restrict__ gammas, int gi)
{
  const int b  = blockIdx.y;
  const int n0 = blockIdx.x * 128;
  __shared__ u16 Au[256][40];
  __shared__ u16 Bu[128][40];
  const int tid = threadIdx.x;
  const int wid = tid >> 6, lane = tid & 63;
  const int lr = lane & 15, lg = lane >> 4;
  const int row0w = (wid & 3) * 64, col0w = (wid >> 2) * 64;

  f32x4 acc[4][4] = {};

  for (int k0 = 0; k0 < 256; k0 += 32) {
    {
      const int m = tid >> 1, kh = (tid & 1) * 16;
      const float* src = catt + ((size_t)(b*CC_ + m))*CC_ + k0 + kh;
      u16 t[16];
      #pragma unroll
      for (int j = 0; j < 4; ++j) {
        const float4 v = *(const float4*)(src + j*4);
        t[j*4]=f2us(v.x); t[j*4+1]=f2us(v.y); t[j*4+2]=f2us(v.z); t[j*4+3]=f2us(v.w);
      }
      *(uint4*)&Au[m][kh]   = *(uint4*)&t[0];
      *(uint4*)&Au[m][kh+8] = *(uint4*)&t[8];
    }
    {
      const int row = tid >> 4;          // k within chunk: 0..31
      const int cg  = (tid & 15) * 8;    // col group: 0,8,...,120
      u16 t[8];
      *(uint4*)t = *(const uint4*)((const u16*)fb +
          ((size_t)(b*CC_ + k0 + row))*HWn + n0 + cg);
      #pragma unroll
      for (int j = 0; j < 8; ++j)
        Bu[cg + j][row] = t[j];
    }
    __syncthreads();
    short8v af[4], bfv[4];
    #pragma unroll
    for (int cf = 0; cf < 4; ++cf)
      af[cf] = *(const short8v*)&Au[row0w + cf*16 + lr][lg*8];
    #pragma unroll
    for (int df = 0; df < 4; ++df)
      bfv[df] = *(const short8v*)&Bu[col0w + df*16 + lr][lg*8];
    #pragma unroll
    for (int cf = 0; cf < 4; ++cf)
      #pragma unroll
      for (int df = 0; df < 4; ++df)
        acc[cf][df] = __builtin_amdgcn_mfma_f32_16x16x32_bf16(
                        af[cf], bfv[df], acc[cf][df], 0, 0, 0);
    __syncthreads();
  }
  const float g = gammas[gi];
  #pragma unroll
  for (int cf = 0; cf < 4; ++cf)
    #pragma unroll
    for (int df = 0; df < 4; ++df)
      #pragma unroll
      for (int r = 0; r < 4; ++r) {
        const int row = row0w + cf*16 + lg*4 + r;
        const int col = n0 + col0w + df*16 + lr;
        const size_t o = ((size_t)(b*CC_ + row))*HWn + col;
        fio[o] = g*acc[cf][df][r] + us2f(((const u16*)fb)[o]);
      }
}

// ---------------------------------------------------------------------------
// MFMA attH: eH[h][g] per (b,w). gl16 staging into [2][128][32].
// ---------------------------------------------------------------------------
__global__ __launch_bounds__(256)
void k_attHm(const bf16* __restrict__ qt, const bf16* __restrict__ kt,
             bf16* __restrict__ att)
{
  const int b = blockIdx.x >> 7, w = blockIdx.x & 127;
  __shared__ __align__(16) u16 Qs[2][128][32];
  __shared__ __align__(16) u16 Ks[2][128][32];
  const int tid = threadIdx.x;
  const int wid = tid >> 6, lane = tid & 63;
  const int lr = lane & 15, lg = lane >> 4;
  const int lrow = lane >> 2, lci = (lane & 3) * 8;
  const int h0w = (wid & 1) * 64, g0w = (wid >> 1) * 64;
  for (int ci = wid; ci < 16; ci += 4) {
    const int seg = ci >> 3, rq = (ci & 7) * 16;
    const int row = rq + lrow;
    const size_t gb = (((size_t)(b*HH + row))*WW + w)*64 + seg*32 + lci;
    gl16((const u16*)qt + gb, &Qs[seg][rq][0]);
    gl16((const u16*)kt + gb, &Ks[seg][rq][0]);
  }
  __syncthreads();
  f32x4 acc[4][4] = {};
  #pragma unroll
  for (int ks = 0; ks < 2; ++ks) {
    short8v af[4], bfv[4];
    #pragma unroll
    for (int hf = 0; hf < 4; ++hf)
      af[hf] = *(const short8v*)&Qs[ks][h0w + hf*16 + lr][lg*8];
    #pragma unroll
    for (int gf = 0; gf < 4; ++gf)
      bfv[gf] = *(const short8v*)&Ks[ks][g0w + gf*16 + lr][lg*8];
    #pragma unroll
    for (int hf = 0; hf < 4; ++hf)
      #pragma unroll
      for (int gf = 0; gf < 4; ++gf)
        acc[hf][gf] = __builtin_amdgcn_mfma_f32_16x16x32_bf16(
                        af[hf], bfv[gf], acc[hf][gf], 0, 0, 0);
  }
  #pragma unroll
  for (int hf = 0; hf < 4; ++hf)
    #pragma unroll
    for (int r = 0; r < 4; ++r) {
      const int h = h0w + hf*16 + lg*4 + r;
      u16* prow = (u16*)att + (((size_t)b*HH + h)*WW + w)*256 + g0w;
      #pragma unroll
      for (int gf = 0; gf < 4; ++gf)
        prow[gf*16 + lr] = f2us(acc[hf][gf][r]);
    }
}

// MFMA attW: eW[w][v] per (b,h). gl16 staging into [2][128][32].
__global__ __launch_bounds__(256)
void k_attWm(const bf16* __restrict__ qt, const bf16* __restrict__ kt,
             bf16* __restrict__ att)
{
  const int b = blockIdx.x >> 7, h = blockIdx.x & 127;
  __shared__ __align__(16) u16 Qs[2][128][32];
  __shared__ __align__(16) u16 Ks[2][128][32];
  const int tid = threadIdx.x;
  const int wid = tid >> 6, lane = tid & 63;
  const int lr = lane & 15, lg = lane >> 4;
  const int lrow = lane >> 2, lci = (lane & 3) * 8;
  const int w0w = (wid & 1) * 64, v0w = (wid >> 1) * 64;
  for (int ci = wid; ci < 16; ci += 4) {
    const int seg = ci >> 3, rq = (ci & 7) * 16;
    const int row = rq + lrow;
    const size_t gb = (((size_t)(b*HH + h))*WW + row)*64 + seg*32 + lci;
    gl16((const u16*)qt + gb, &Qs[seg][rq][0]);
    gl16((const u16*)kt + gb, &Ks[seg][rq][0]);
  }
  __syncthreads();
  f32x4 acc[4][4] = {};
  #pragma unroll
  for (int ks = 0; ks < 2; ++ks) {
    short8v af[4], bfv[4];
    #pragma unroll
    for (int wf = 0; wf < 4; ++wf)
      af[wf] = *(const short8v*)&Qs[ks][w0w + wf*16 + lr][lg*8];
    #pragma unroll
    for (int vf = 0; vf < 4; ++vf)
      bfv[vf] = *(const short8v*)&Ks[ks][v0w + vf*16 + lr][lg*8];
    #pragma unroll
    for (int wf = 0; wf < 4; ++wf)
      #pragma unroll
      for (int vf = 0; vf < 4; ++vf)
        acc[wf][vf] = __builtin_amdgcn_mfma_f32_16x16x32_bf16(
                        af[wf], bfv[vf], acc[wf][vf], 0, 0, 0);
  }
  #pragma unroll
  for (int wf = 0; wf < 4; ++wf)
    #pragma unroll
    for (int r = 0; r < 4; ++r) {
      const int wloc = w0w + wf*16 + lg*4 + r;
      u16* prow = (u16*)att + ((((size_t)b*HH + h)*WW + wloc)*256 + 128) + v0w;
      #pragma unroll
      for (int vf = 0; vf < 4; ++vf)
        prow[vf*16 + lr] = f2us(acc[wf][vf][r]);
    }
}

// softmax over 256 bf16 per pixel, in place. One wave per row.
__global__ __launch_bounds__(256)
void k_ccsm(bf16* __restrict__ att)
{
  const int row  = blockIdx.x * 4 + (threadIdx.x >> 6);
  const int lane = threadIdx.x & 63;
  u16* __restrict__ p = (u16*)att + (size_t)row * 256 + lane * 4;
  const ushort4 u = *(const ushort4*)p;
  float v0 = us2f(u.x), v1 = us2f(u.y), v2 = us2f(u.z), v3 = us2f(u.w);
  float m = fmaxf(fmaxf(v0, v1), fmaxf(v2, v3));
  #pragma unroll
  for (int o = 32; o; o >>= 1) m = fmaxf(m, __shfl_xor(m, o, 64));
  const float e0 = __expf(v0-m), e1 = __expf(v1-m), e2 = __expf(v2-m), e3 = __expf(v3-m);
  float s = e0 + e1 + e2 + e3;
  #pragma unroll
  for (int o = 32; o; o >>= 1) s += __shfl_xor(s, o, 64);
  const float inv = 1.f / s;
  st4((bf16*)p, e0*inv, e1*inv, e2*inv, e3*inv);
}

// ---------------------------------------------------------------------------
// MFMA outW: yt[w][c] = sum_v att[w][128+v] * V[v][c] per (b,h).
// ---------------------------------------------------------------------------
__global__ __launch_bounds__(256)
void k_outWm(const bf16* __restrict__ vt, const bf16* __restrict__ att,
             bf16* __restrict__ yt)
{
  const int b = blockIdx.y >> 7, h = blockIdx.y & 127;
  const int ch0 = blockIdx.x * 128;
  __shared__ u16 As[128][72];   // [w][v-chunk]
  __shared__ u16 Bs[128][72];   // [c][v-chunk] (transposed V)
  const int tid = threadIdx.x;
  const int wid = tid >> 6, lane = tid & 63;
  const int lr = lane & 15, lg = lane >> 4;
  const int w0w = (wid & 1) * 64, c0w = (wid >> 1) * 64;

  f32x4 acc[4][4] = {};

  for (int v0 = 0; v0 < 128; v0 += 64) {
    {
      const int row = tid >> 1, kq = (tid & 1) * 32;
      const u16* src = (const u16*)att + ((((size_t)b*HH + h)*WW + row)*256 + 128) + v0 + kq;
      #pragma unroll
      for (int j = 0; j < 4; ++j)
        *(uint4*)&As[row][kq + j*8] = *(const uint4*)(src + j*8);
    }
    {
      const int vv = tid & 63, cg0 = (tid >> 6) * 32;
      #pragma unroll
      for (int j2 = 0; j2 < 4; ++j2) {
        const int c8 = cg0 + j2*8;
        u16 t[8];
        *(uint4*)t = *(const uint4*)((const u16*)vt +
            (((size_t)(b*HH + h))*WW + (v0 + vv))*256 + ch0 + c8);
        #pragma unroll
        for (int jj = 0; jj < 8; ++jj) Bs[c8 + jj][vv] = t[jj];
      }
    }
    __syncthreads();
    #pragma unroll
    for (int ks = 0; ks < 2; ++ks) {
      short8v af[4], bfv[4];
      #pragma unroll
      for (int wf = 0; wf < 4; ++wf)
        af[wf] = *(const short8v*)&As[w0w + wf*16 + lr][ks*32 + lg*8];
      #pragma unroll
      for (int cf = 0; cf < 4; ++cf)
        bfv[cf] = *(const short8v*)&Bs[c0w + cf*16 + lr][ks*32 + lg*8];
      #pragma unroll
      for (int wf = 0; wf < 4; ++wf)
        #pragma unroll
        for (int cf = 0; cf < 4; ++cf)
          acc[wf][cf] = __builtin_amdgcn_mfma_f32_16x16x32_bf16(
                          af[wf], bfv[cf], acc[wf][cf], 0, 0, 0);
    }
    __syncthreads();
  }
  #pragma unroll
  for (int wf = 0; wf < 4; ++wf)
    #pragma unroll
    for (int r = 0; r < 4; ++r) {
      const int wpix = w0w + wf*16 + lg*4 + r;
      u16* drow = (u16*)yt + (((size_t)(b*HH + h))*WW + wpix)*256 + ch0 + c0w;
      #pragma unroll
      for (int cf = 0; cf < 4; ++cf)
        drow[cf*16 + lr] = f2us(acc[wf][cf][r]);
    }
}

// MFMA outH: xt[h][c] = yt[h][c] + sum_g att[h][g] * V[(g,w)][c] per (b,w).
__global__ __launch_bounds__(256)
void k_outHm(const bf16* __restrict__ vt, const bf16* __restrict__ att,
             const bf16* __restrict__ yt, bf16* __restrict__ xt)
{
  const int b = blockIdx.y >> 7, w = blockIdx.y & 127;
  const int ch0 = blockIdx.x * 128;
  __shared__ u16 As[128][72];   // [h][g-chunk]
  __shared__ u16 Bs[128][72];   // [c][g-chunk] (transposed V)
  const int tid = threadIdx.x;
  const int wid = tid >> 6, lane = tid & 63;
  const int lr = lane & 15, lg = lane >> 4;
  const int h0w = (wid & 1) * 64, c0w = (wid >> 1) * 64;

  f32x4 acc[4][4] = {};

  for (int g0 = 0; g0 < 128; g0 += 64) {
    {
      const int row = tid >> 1, kq = (tid & 1) * 32;
      const u16* src = (const u16*)att + (((size_t)b*HH + row)*WW + w)*256 + g0 + kq;
      #pragma unroll
      for (int j = 0; j < 4; ++j)
        *(uint4*)&As[row][kq + j*8] = *(const uint4*)(src + j*8);
    }
    {
      const int gg = tid & 63, cg0 = (tid >> 6) * 32;
      #pragma unroll
      for (int j2 = 0; j2 < 4; ++j2) {
        const int c8 = cg0 + j2*8;
        u16 t[8];
        *(uint4*)t = *(const uint4*)((const u16*)vt +
            (((size_t)(b*HH + (g0 + gg)))*WW + w)*256 + ch0 + c8);
        #pragma unroll
        for (int jj = 0; jj < 8; ++jj) Bs[c8 + jj][gg] = t[jj];
      }
    }
    __syncthreads();
    #pragma unroll
    for (int ks = 0; ks < 2; ++ks) {
      short8v af[4], bfv[4];
      #pragma unroll
      for (int hf = 0; hf < 4; ++hf)
        af[hf] = *(const short8v*)&As[h0w + hf*16 + lr][ks*32 + lg*8];
      #pragma unroll
      for (int cf = 0; cf < 4; ++cf)
        bfv[cf] = *(const short8v*)&Bs[c0w + cf*16 + lr][ks*32 + lg*8];
      #pragma unroll
      for (int hf = 0; hf < 4; ++hf)
        #pragma unroll
        for (int cf = 0; cf < 4; ++cf)
          acc[hf][cf] = __builtin_amdgcn_mfma_f32_16x16x32_bf16(
                          af[hf], bfv[cf], acc[hf][cf], 0, 0, 0);
    }
    __syncthreads();
  }
  #pragma unroll
  for (int hf = 0; hf < 4; ++hf)
    #pragma unroll
    for (int r = 0; r < 4; ++r) {
      const int hh = h0w + hf*16 + lg*4 + r;
      const size_t base = (((size_t)(b*HH + hh))*WW + w)*256 + ch0 + c0w;
      #pragma unroll
      for (int cf = 0; cf < 4; ++cf) {
        const size_t o = base + cf*16 + lr;
        ((u16*)xt)[o] = f2us(acc[hf][cf][r] + us2f(((const u16*)yt)[o]));
      }
    }
}

// scale + softmax over d, in place f32. rown holds raw sumsq (sqrt here).
__global__ __launch_bounds__(256)
void k_camsm(float* __restrict__ energy, const float* __restrict__ rown)
{
  const int row  = blockIdx.x * 4 + (threadIdx.x >> 6);
  const int lane = threadIdx.x & 63;
  const int b = row >> 8;
  float* __restrict__ p = energy + (size_t)row * 256 + lane * 4;
  const float rc = sqrtf(rown[row]) + 1e-10f;
  float4 rd = *(const float4*)(rown + b*256 + lane*4);
  rd.x = sqrtf(rd.x) + 1e-10f; rd.y = sqrtf(rd.y) + 1e-10f;
  rd.z = sqrtf(rd.z) + 1e-10f; rd.w = sqrtf(rd.w) + 1e-10f;
  float4 v = *(const float4*)p;
  v.x /= (rc*rd.x); v.y /= (rc*rd.y); v.z /= (rc*rd.z); v.w /= (rc*rd.w);
  float m = fmaxf(fmaxf(v.x, v.y), fmaxf(v.z, v.w));
  #pragma unroll
  for (int o = 32; o; o >>= 1) m = fmaxf(m, __shfl_xor(m, o, 64));
  const float e0 = __expf(v.x-m), e1 = __expf(v.y-m), e2 = __expf(v.z-m), e3 = __expf(v.w-m);
  float s = e0 + e1 + e2 + e3;
  #pragma unroll
  for (int o = 32; o; o >>= 1) s += __shfl_xor(s, o, 64);
  const float inv = 1.f / s;
  *(float4*)p = make_float4(e0*inv, e1*inv, e2*inv, e3*inv);
}

// ---------------------------------------------------------------------------
extern "C" void kernel_launch(void* const* d_in, const int* in_sizes, int n_in,
                              void* d_out, int out_size, void* d_ws, size_t ws_size,
                              hipStream_t stream)
{
  const float* x     = (const float*)d_in[0];
  const float* w_[5]  = {(const float*)d_in[1],(const float*)d_in[2],(const float*)d_in[3],(const float*)d_in[4],(const float*)d_in[5]};
  const float* s_[5]  = {(const float*)d_in[6],(const float*)d_in[7],(const float*)d_in[8],(const float*)d_in[9],(const float*)d_in[10]};
  const float* bi_[5] = {(const float*)d_in[11],(const float*)d_in[12],(const float*)d_in[13],(const float*)d_in[14],(const float*)d_in[15]};
  const float* wq = (const float*)d_in[16];
  const float* bq = (const float*)d_in[17];
  const float* wk = (const float*)d_in[18];
  const float* bk = (const float*)d_in[19];
  const float* wv = (const float*)d_in[20];
  const float* bv = (const float*)d_in[21];
  const float* gam = (const float*)d_in[22];
  float* out = (float*)d_out;   // f32, 5 slots of SZ

  // Workspace layout (~155 MB, proven envelope; CC buffers disjoint).
  // stats(128f) | energy(262144f) | rown(1024f) are contiguous -> one memset.
  char* wsc = (char*)d_ws;
  bf16*  Tc16 = (bf16*)wsc;
  bf16*  qt   = (bf16*)wsc;
  bf16*  kt   = qt + SZ/4;
  bf16*  vt   = qt + SZ/2;
  bf16*  attb = qt + SZ/2 + SZ;
  bf16*  xt   = attb + SZ;
  bf16*  yt   = xt + SZ;
  bf16*  wtb  = yt + SZ;
  bf16*  wtq  = wtb;
  bf16*  wtk  = wtb + 16384;
  bf16*  wtv  = wtb + 32768;
  float* stats  = (float*)(wtb + 16*65536);
  float* energy = stats + 128;
  float* rown   = energy + 262144;
  float* slot4 = out + 4*SZ;
  bf16*  fbA   = attb;  // branches 0-3: bf16 GN output (CAM input)
  bf16*  fb16  = vt;    // branch 4: bf16 CC output copy (CAM input)

  const int dil_[5] = {1, 6, 12, 18, 1};

  // ---- branches 0-3: fused ASPP + CAM (stats/rown fused into conv/apply) --
  k_xpose<<<512,256,0,stream>>>(x, xt);
  for (int i = 0; i < 4; ++i) {
    hipMemsetAsync(stats, 0, (size_t)(128 + 262144 + 1024)*sizeof(float), stream);
    const int taps = (i == 0) ? 1 : 9;
    k_wt<<<taps*256,256,0,stream>>>(w_[i], wtb, taps);
    if (i == 0) k_convm<1,bf16,false,true,false><<<dim3(4,512),256,0,stream>>>(xt, wtb, nullptr, Tc16, 1, 256, stats);
    else        k_convm<3,bf16,false,true,false><<<dim3(4,512),256,0,stream>>>(xt, wtb, nullptr, Tc16, dil_[i], 256, stats);
    k_gn_applyb<<<16384,256,0,stream>>>(Tc16, stats, s_[i], bi_[i], fbA, rown);
    k_energym<<<dim3(4,32,4),256,0,stream>>>(fbA, energy);
    k_camsm<<<256,256,0,stream>>>(energy, rown);
    k_camoutm<<<dim3(128,4),512,0,stream>>>(energy, fbA, out + (size_t)i*SZ, gam, i);
  }

  // ---- branch 4 ASPP: conv (fused stats) -> fused GN+transpose -> xt ----
  {
    hipMemsetAsync(stats, 0, 128*sizeof(float), stream);
    k_wt<<<9*256,256,0,stream>>>(w_[4], wtb, 9);
    k_convm<3,bf16,false,true,false><<<dim3(4,512),256,0,stream>>>(xt, wtb, nullptr, Tc16, 1, 256, stats);
    k_xpose_gn<<<512,256,0,stream>>>(Tc16, stats, s_[4], bi_[4], xt);
  }

  // ---- criss-cross attention x2, fully c-last; all GEMMs via MFMA.
  //      q/k convs carry the fused per-pixel L2-norm (QKNORM). ----
  k_wt<<<64,256,0,stream>>>(wq, wtq, 1);
  k_wt<<<64,256,0,stream>>>(wk, wtk, 1);
  k_wt<<<256,256,0,stream>>>(wv, wtv, 1);
  for (int it = 0; it < 2; ++it) {
    k_convm<1,bf16,true,false,true><<<dim3(1,512),256,0,stream>>>(xt, wtq, bq, qt, 1, 64, nullptr);
    k_convm<1,bf16,true,false,true><<<dim3(1,512),256,0,stream>>>(xt, wtk, bk, kt, 1, 64, nullptr);
    k_convm<1,bf16,true,false,false><<<dim3(4,512),256,0,stream>>>(xt, wtv, bv, vt, 1, 256, nullptr);
    k_attHm<<<512,256,0,stream>>>(qt, kt, attb);
    k_attWm<<<512,256,0,stream>>>(qt, kt, attb);
    k_ccsm<<<16384,256,0,stream>>>(attb);
    k_outWm<<<dim3(2,512),256,0,stream>>>(vt, attb, yt);
    k_outHm<<<dim3(2,512),256,0,stream>>>(vt, attb, yt, xt);
  }

  // ---- CAM on branch 4: xt -> bf16 NCHW copy with fused row-sumsq ----
  {
    hipMemsetAsync(energy, 0, (size_t)(262144 + 1024)*sizeof(float), stream);
    k_xposeb_b<<<512,256,0,stream>>>(xt, fb16, rown);
    k_energym<<<dim3(4,32,4),256,0,stream>>>(fb16, energy);
    k_camsm<<<256,256,0,stream>>>(energy, rown);
    k_camoutm<<<dim3(128,4),512,0,stream>>>(energy, fb16, slot4, gam, 4);
  }
}

// Round 27
// 1312.435 us; speedup vs baseline: 1.0362x; 1.0362x over previous
//
#include <hip/hip_runtime.h>
#include <hip/hip_bf16.h>

typedef __hip_bfloat16 bf16;
typedef unsigned short u16;
typedef __attribute__((ext_vector_type(8))) short short8v;  // 8 bf16 (4 VGPR)
typedef __attribute__((ext_vector_type(4))) float f32x4;

#define BB   4
#define CC_  256
#define HH   128
#define WW   128
#define HWn  16384
#define SZ   ((size_t)16777216)   // BB*CC_*HWn elements per slot

__device__ __forceinline__ float b2f(bf16 v){ return __bfloat162float(v); }
__device__ __forceinline__ bf16  f2b(float v){ return __float2bfloat16(v); }
__device__ __forceinline__ float us2f(u16 u){
  union { unsigned int i; float f; } x; x.i = ((unsigned int)u) << 16; return x.f;
}
__device__ __forceinline__ u16 f2us(float v){
  bf16 h = f2b(v); u16 u; __builtin_memcpy(&u, &h, 2); return u;
}
__device__ __forceinline__ void st4(float* p, float a, float b, float c, float d){
  *(float4*)p = make_float4(a,b,c,d);
}
__device__ __forceinline__ void st4(bf16* p, float a, float b, float c, float d){
  bf16 o[4] = { f2b(a), f2b(b), f2b(c), f2b(d) };
  *(uint2*)p = *(uint2*)o;
}
__device__ __forceinline__ void store1(float* p, float v){ *p = v; }
__device__ __forceinline__ void store1(bf16* p, float v){ *p = f2b(v); }

// Direct global->LDS 16B async load (per-lane global src, wave-uniform LDS
// base; lane i lands at base + i*16B).
typedef __attribute__((address_space(1))) const unsigned int u32g;
typedef __attribute__((address_space(3))) unsigned int u32l;
__device__ __forceinline__ void gl16(const void* g, void* l)
{
  u32g* gp = (u32g*)(unsigned long long)(size_t)g;
  u32l* lp = (u32l*)(unsigned int)(size_t)l;
  __builtin_amdgcn_global_load_lds(gp, lp, 16, 0, 0);
}

// ---------------------------------------------------------------------------
// Transpose [B,256,H,W] f32 -> [B,H,W,256] bf16. One block per (b,h).
// ---------------------------------------------------------------------------
__global__ __launch_bounds__(256)
void k_xpose(const float* __restrict__ x, bf16* __restrict__ xt)
{
  const int b = blockIdx.x >> 7, h = blockIdx.x & 127;
  __shared__ u16 L[64][132];
  const int tid = threadIdx.x;
  for (int c0 = 0; c0 < 256; c0 += 64) {
    for (int idx = tid; idx < 2048; idx += 256) {
      const int c = idx >> 5, w4 = (idx & 31) * 4;
      const float4 v = *(const float4*)&x[(((size_t)(b*CC_ + c0 + c))*HH + h)*WW + w4];
      L[c][w4]   = f2us(v.x); L[c][w4+1] = f2us(v.y);
      L[c][w4+2] = f2us(v.z); L[c][w4+3] = f2us(v.w);
    }
    __syncthreads();
    for (int idx = tid; idx < 1024; idx += 256) {
      const int w = idx >> 3, cg = (idx & 7) * 8;
      u16 tmp[8];
      #pragma unroll
      for (int j = 0; j < 8; ++j) tmp[j] = L[cg + j][w];
      *(uint4*)&xt[(((size_t)(b*HH + h))*WW + w)*256 + c0 + cg] = *(uint4*)tmp;
    }
    __syncthreads();
  }
}

// Fused GN-apply + transpose (branch 4): Tc16 [B,C,H,W] bf16 + stats ->
// xt [B,H,W,256] bf16.
__global__ __launch_bounds__(256)
void k_xpose_gn(const bf16* __restrict__ t, const float* __restrict__ stats,
                const float* __restrict__ sc, const float* __restrict__ bi,
                bf16* __restrict__ xt)
{
  const int b = blockIdx.x >> 7, h = blockIdx.x & 127;
  __shared__ u16 L[64][132];
  const int tid = threadIdx.x;
  const float cnt = 16.f * 16384.f;
  for (int c0 = 0; c0 < 256; c0 += 64) {
    for (int idx = tid; idx < 1024; idx += 256) {
      const int c = idx >> 4, w8 = (idx & 15) * 8;
      const int cg = c0 + c;
      const int bg = b*16 + (cg >> 4);
      const float mu  = stats[bg*2] / cnt;
      const float var = stats[bg*2+1] / cnt - mu * mu;
      const float a   = rsqrtf(var + 1e-5f) * sc[cg];
      const float bb  = bi[cg] - mu * a;
      u16 t8[8];
      *(uint4*)t8 = *(const uint4*)((const u16*)t + (((size_t)(b*CC_ + cg))*HH + h)*WW + w8);
      #pragma unroll
      for (int j = 0; j < 8; ++j) t8[j] = f2us(fmaxf(us2f(t8[j])*a + bb, 0.f));
      #pragma unroll
      for (int j = 0; j < 8; ++j) L[c][w8 + j] = t8[j];
    }
    __syncthreads();
    for (int idx = tid; idx < 1024; idx += 256) {
      const int w = idx >> 3, cg = (idx & 7) * 8;
      u16 tmp[8];
      #pragma unroll
      for (int j = 0; j < 8; ++j) tmp[j] = L[cg + j][w];
      *(uint4*)&xt[(((size_t)(b*HH + h))*WW + w)*256 + c0 + cg] = *(uint4*)tmp;
    }
    __syncthreads();
  }
}

// Inverse for branch-4 CC output: [B,H,W,256] bf16 -> [B,256,H,W] bf16,
// with fused CAM row-sumsq (32-lane-group reduce + 1 atomic per (b,c)).
__global__ __launch_bounds__(256)
void k_xposeb_b(const bf16* __restrict__ xt, bf16* __restrict__ fb,
                float* __restrict__ rownsq)
{
  const int b = blockIdx.x >> 7, h = blockIdx.x & 127;
  __shared__ u16 L[64][132];
  const int tid = threadIdx.x;
  for (int c0 = 0; c0 < 256; c0 += 64) {
    for (int idx = tid; idx < 1024; idx += 256) {
      const int w = idx >> 3, cg = (idx & 7) * 8;
      u16 t[8];
      *(uint4*)t = *(const uint4*)((const u16*)xt + (((size_t)(b*HH + h))*WW + w)*256 + c0 + cg);
      #pragma unroll
      for (int j = 0; j < 8; ++j) L[cg + j][w] = t[j];
    }
    __syncthreads();
    for (int idx = tid; idx < 2048; idx += 256) {
      const int c = idx >> 5, w4 = (idx & 31) * 4;
      u16 q[4] = { L[c][w4], L[c][w4+1], L[c][w4+2], L[c][w4+3] };
      *(uint2*)((u16*)fb + (((size_t)(b*CC_ + c0 + c))*HH + h)*WW + w4) = *(uint2*)q;
      float sq = 0.f;
      #pragma unroll
      for (int j = 0; j < 4; ++j) { const float v = us2f(q[j]); sq = fmaf(v, v, sq); }
      #pragma unroll
      for (int o = 16; o > 0; o >>= 1) sq += __shfl_xor(sq, o, 64);
      if ((tid & 31) == 0) atomicAdd(&rownsq[b*256 + c0 + c], sq);
    }
    __syncthreads();
  }
}

// Weights [CO,CI,taps] f32 -> wt [taps,CO,CI] bf16.
__global__ __launch_bounds__(256)
void k_wt(const float* __restrict__ w, bf16* __restrict__ wt, int taps)
{
  const int i = blockIdx.x * 256 + threadIdx.x;
  const int tap = i >> 16, r = i & 65535;
  const int co = r >> 8, ci = r & 255;
  if (tap < taps) wt[i] = f2b(w[(co*256 + ci)*taps + tap]);
}

// ---------------------------------------------------------------------------
// MFMA conv with global_load_lds staging (r21 proven). LDS linear [rows][32].
// STATS: fused GroupNorm stats (r23 proven).
// QKNORM (TRANS, CO==64, grid.x==1): fused per-pixel L2-normalize over the
// 64 output channels (replaces k_qknorm_t).
// ---------------------------------------------------------------------------
template<int KHW, typename DT, bool TRANS, bool STATS, bool QKNORM>
__global__ __launch_bounds__(256)
void k_convm(const bf16* __restrict__ xt, const bf16* __restrict__ wt,
             const float* __restrict__ bias, DT* __restrict__ dst, int dil, int CO,
             float* __restrict__ stats)
{
  const int b   = blockIdx.y >> 7;
  const int h   = blockIdx.y & 127;
  const int co0 = blockIdx.x * 64;
  const int tid = threadIdx.x;
  const int wid = tid >> 6;
  const int lane = tid & 63;
  const int lr = lane & 15;
  const int lg = lane >> 4;
  const int lrow = lane >> 2;        // row within 16-row chunk
  const int lci  = (lane & 3) * 8;   // 16B slot (8 u16) within row

  __shared__ __align__(16) u16 Asld[KHW*64][32];
  __shared__ __align__(16) u16 Bsld[164][32];

  // Pre-zero the constant pad rows of B (0..17 and 146..163).
  for (int i = tid; i < 36*32; i += 256) {
    int r = i >> 5; r = (r < 18) ? r : (128 + r);
    Bsld[r][i & 31] = 0;
  }

  f32x4 acc[4][2] = {};

  for (int kh = 0; kh < KHW; ++kh) {
    const int hh = h + (kh - (KHW >> 1)) * dil;
    if (hh < 0 || hh >= HH) continue;
    const bf16* __restrict__ brow = xt + ((size_t)(b*HH + hh))*WW*256;
    for (int kc = 0; kc < 256; kc += 32) {
      for (int ch = wid; ch < KHW*4; ch += 4) {
        const int row = ch*16 + lrow;
        const int tap = row >> 6, cc = row & 63;
        gl16(wt + ((size_t)(kh*KHW + tap))*CO*256 + (co0 + cc)*256 + kc + lci,
             &Asld[ch*16][0]);
      }
      for (int ch = wid; ch < 8; ch += 4) {
        const int wpos = ch*16 + lrow;
        gl16(brow + (size_t)wpos*256 + kc + lci, &Bsld[18 + ch*16][0]);
      }
      __syncthreads();
      #pragma unroll
      for (int kw = 0; kw < KHW; ++kw) {
        const int pbase = 18 + (kw - (KHW >> 1)) * dil;
        short8v af[4], bfr[2];
        #pragma unroll
        for (int cf = 0; cf < 4; ++cf)
          af[cf] = *(const short8v*)&Asld[kw*64 + cf*16 + lr][lg*8];
        #pragma unroll
        for (int wf = 0; wf < 2; ++wf)
          bfr[wf] = *(const short8v*)&Bsld[pbase + wid*32 + wf*16 + lr][lg*8];
        #pragma unroll
        for (int cf = 0; cf < 4; ++cf)
          #pragma unroll
          for (int wf = 0; wf < 2; ++wf)
            acc[cf][wf] = __builtin_amdgcn_mfma_f32_16x16x32_bf16(
                            af[cf], bfr[wf], acc[cf][wf], 0, 0, 0);
      }
      __syncthreads();
    }
  }
  if constexpr (TRANS) {
    if constexpr (QKNORM) {
      // CO==64, co0==0. Fused per-pixel L2-norm over 64 channels.
      #pragma unroll
      for (int wf = 0; wf < 2; ++wf) {
        float vr[16];
        float sq = 0.f;
        #pragma unroll
        for (int cf = 0; cf < 4; ++cf)
          #pragma unroll
          for (int r = 0; r < 4; ++r) {
            const float v = us2f(f2us(acc[cf][wf][r] + bias[cf*16 + lg*4 + r]));
            vr[cf*4 + r] = v;
            sq = fmaf(v, v, sq);
          }
        sq += __shfl_xor(sq, 16, 64);
        sq += __shfl_xor(sq, 32, 64);
        const float rn = 1.f / (sqrtf(sq) + 1e-10f);
        const int wpix = wid*32 + wf*16 + lr;
        bf16* dr = (bf16*)dst + (((size_t)(b*HH + h))*WW + wpix)*CO + lg*4;
        #pragma unroll
        for (int cf = 0; cf < 4; ++cf) {
          bf16 o4[4];
          #pragma unroll
          for (int r = 0; r < 4; ++r) o4[r] = f2b(vr[cf*4 + r] * rn);
          *(uint2*)(dr + cf*16) = *(uint2*)o4;
        }
      }
    } else {
      #pragma unroll
      for (int cf = 0; cf < 4; ++cf) {
        float bb[4];
        #pragma unroll
        for (int r = 0; r < 4; ++r)
          bb[r] = bias ? bias[co0 + cf*16 + lg*4 + r] : 0.f;
        #pragma unroll
        for (int wf = 0; wf < 2; ++wf) {
          const int wpix = wid*32 + wf*16 + lr;
          bf16* dr = (bf16*)dst + (((size_t)(b*HH + h))*WW + wpix)*CO + co0 + cf*16 + lg*4;
          bf16 o4[4];
          #pragma unroll
          for (int r = 0; r < 4; ++r) o4[r] = f2b(acc[cf][wf][r] + bb[r]);
          *(uint2*)dr = *(uint2*)o4;
        }
      }
    }
  } else {
    float s0[4] = {0.f,0.f,0.f,0.f}, s1[4] = {0.f,0.f,0.f,0.f};
    #pragma unroll
    for (int cf = 0; cf < 4; ++cf) {
      #pragma unroll
      for (int r = 0; r < 4; ++r) {
        const int co = co0 + cf*16 + lg*4 + r;
        const float bb = bias ? bias[co] : 0.f;
        DT* drow = dst + (((size_t)(b*CO + co))*HH + h)*WW;
        #pragma unroll
        for (int wf = 0; wf < 2; ++wf) {
          const float v = acc[cf][wf][r] + bb;
          store1(drow + wid*32 + wf*16 + lr, v);
          if constexpr (STATS) {
            const float vr = us2f(f2us(v));   // rounded value, as stored
            s0[cf] += vr;
            s1[cf] = fmaf(vr, vr, s1[cf]);
          }
        }
      }
    }
    if constexpr (STATS) {
      #pragma unroll
      for (int cf = 0; cf < 4; ++cf)
        #pragma unroll
        for (int o = 32; o > 0; o >>= 1) {
          s0[cf] += __shfl_down(s0[cf], o, 64);
          s1[cf] += __shfl_down(s1[cf], o, 64);
        }
      __shared__ float sred[4][4][2];
      if (lane == 0) {
        #pragma unroll
        for (int cf = 0; cf < 4; ++cf) { sred[wid][cf][0] = s0[cf]; sred[wid][cf][1] = s1[cf]; }
      }
      __syncthreads();
      if (tid < 8) {
        const int cf = tid >> 1, j = tid & 1;
        const float t = sred[0][cf][j] + sred[1][cf][j] + sred[2][cf][j] + sred[3][cf][j];
        atomicAdd(&stats[(b*16 + (co0 >> 4) + cf)*2 + j], t);
      }
    }
  }
}

// GroupNorm apply -> bf16 (branches 0-3), fused CAM row-sumsq.
__global__ __launch_bounds__(256)
void k_gn_applyb(const bf16* __restrict__ t, const float* __restrict__ stats,
                 const float* __restrict__ sc, const float* __restrict__ bi,
                 bf16* __restrict__ dst, float* __restrict__ rownsq)
{
  const size_t e = ((size_t)blockIdx.x * 256 + threadIdx.x) * 4;
  const int c  = (int)((e >> 14) & 255);
  const int bg = (int)(e >> 22) * 16 + (c >> 4);
  const float cnt = 16.f * 16384.f;
  const float mu  = stats[bg*2] / cnt;
  const float var = stats[bg*2+1] / cnt - mu * mu;
  const float rs  = rsqrtf(var + 1e-5f);
  const float a   = rs * sc[c];
  const float bb  = bi[c] - mu * a;
  const ushort4 u = *(const ushort4*)((const u16*)t + e);
  u16 q[4] = { f2us(fmaxf(us2f(u.x)*a+bb,0.f)), f2us(fmaxf(us2f(u.y)*a+bb,0.f)),
               f2us(fmaxf(us2f(u.z)*a+bb,0.f)), f2us(fmaxf(us2f(u.w)*a+bb,0.f)) };
  *(uint2*)((u16*)dst + e) = *(uint2*)q;
  float sq = 0.f;
  #pragma unroll
  for (int j = 0; j < 4; ++j) { const float w = us2f(q[j]); sq = fmaf(w, w, sq); }
  #pragma unroll
  for (int o = 32; o > 0; o >>= 1) sq += __shfl_down(sq, o, 64);
  __shared__ float sh[4];
  const int wid = threadIdx.x >> 6, lane = threadIdx.x & 63;
  if (lane == 0) sh[wid] = sq;
  __syncthreads();
  if (threadIdx.x == 0) atomicAdd(&rownsq[blockIdx.x >> 4], sh[0]+sh[1]+sh[2]+sh[3]);
}

// ---------------------------------------------------------------------------
// MFMA energy: E[b] += F.F^T (bf16 copy of slot). Tile 128x128, split-K 32
// (k-chunk 512). gl16 staging into segmented LDS [2][128][32]. Full 4 tiles.
// ---------------------------------------------------------------------------
__global__ __launch_bounds__(256)
void k_energym(const bf16* __restrict__ fb, float* __restrict__ energy)
{
  const int b  = blockIdx.z;
  const int c0 = (blockIdx.x >> 1) * 128, d0 = (blockIdx.x & 1) * 128;
  const int k0 = blockIdx.y * 512;
  __shared__ __align__(16) u16 Au[2][128][32];
  __shared__ __align__(16) u16 Bu[2][128][32];
  const int tid = threadIdx.x;
  const int wid = tid >> 6, lane = tid & 63;
  const int lr = lane & 15, lg = lane >> 4;
  const int lrow = lane >> 2, lci = (lane & 3) * 8;
  const int row0w = (wid & 1) * 64, col0w = (wid >> 1) * 64;
  const u16* __restrict__ fbb = (const u16*)fb + (size_t)b * CC_ * HWn;

  f32x4 acc[4][4] = {};

  for (int kc = 0; kc < 512; kc += 64) {
    for (int ci = wid; ci < 16; ci += 4) {
      const int seg = ci >> 3, rq = (ci & 7) * 16;
      const int m = rq + lrow;
      gl16(fbb + (size_t)(c0 + m)*HWn + k0 + kc + seg*32 + lci, &Au[seg][rq][0]);
      gl16(fbb + (size_t)(d0 + m)*HWn + k0 + kc + seg*32 + lci, &Bu[seg][rq][0]);
    }
    __syncthreads();
    #pragma unroll
    for (int ks = 0; ks < 2; ++ks) {
      short8v af[4], bfv[4];
      #pragma unroll
      for (int cf = 0; cf < 4; ++cf)
        af[cf] = *(const short8v*)&Au[ks][row0w + cf*16 + lr][lg*8];
      #pragma unroll
      for (int df = 0; df < 4; ++df)
        bfv[df] = *(const short8v*)&Bu[ks][col0w + df*16 + lr][lg*8];
      #pragma unroll
      for (int cf = 0; cf < 4; ++cf)
        #pragma unroll
        for (int df = 0; df < 4; ++df)
          acc[cf][df] = __builtin_amdgcn_mfma_f32_16x16x32_bf16(
                          af[cf], bfv[df], acc[cf][df], 0, 0, 0);
    }
    __syncthreads();
  }
  #pragma unroll
  for (int cf = 0; cf < 4; ++cf)
    #pragma unroll
    for (int df = 0; df < 4; ++df)
      #pragma unroll
      for (int r = 0; r < 4; ++r) {
        const int row = c0 + row0w + cf*16 + lg*4 + r;
        const int col = d0 + col0w + df*16 + lr;
        atomicAdd(&energy[((size_t)(b*CC_ + row))*CC_ + col], acc[cf][df][r]);
      }
}

// ---------------------------------------------------------------------------
// MFMA camout: out = gamma*(att@f) + f. B and residual from bf16 copy.
// B staging: r23-proven pattern (16-lane 32B-contiguous reads, bank-spread
// LDS writes). r26's "coalesced" variant had 16-way LDS write conflicts.
// ---------------------------------------------------------------------------
__global__ __launch_bounds__(512)
void k_camoutm(const float* __restrict__ catt, const bf16* __restrict__ fb,
               float* __restrict__ fio, const float* __restrict__ gammas, int gi)
{
  const int b  = blockIdx.y;
  const int n0 = blockIdx.x * 128;
  __shared__ u16 Au[256][40];
  __shared__ u16 Bu[128][40];
  const int tid = threadIdx.x;
  const int wid = tid >> 6, lane = tid & 63;
  const int lr = lane & 15, lg = lane >> 4;
  const int row0w = (wid & 3) * 64, col0w = (wid >> 2) * 64;

  f32x4 acc[4][4] = {};

  for (int k0 = 0; k0 < 256; k0 += 32) {
    {
      const int m = tid >> 1, kh = (tid & 1) * 16;
      const float* src = catt + ((size_t)(b*CC_ + m))*CC_ + k0 + kh;
      u16 t[16];
      #pragma unroll
      for (int j = 0; j < 4; ++j) {
        const float4 v = *(const float4*)(src + j*4);
        t[j*4]=f2us(v.x); t[j*4+1]=f2us(v.y); t[j*4+2]=f2us(v.z); t[j*4+3]=f2us(v.w);
      }
      *(uint4*)&Au[m][kh]   = *(uint4*)&t[0];
      *(uint4*)&Au[m][kh+8] = *(uint4*)&t[8];
    }
    {
      const int kk = tid >> 4, cl = tid & 15;
      const u16* src = (const u16*)fb + ((size_t)(b*CC_ + k0 + kk))*HWn + n0 + cl;
      #pragma unroll
      for (int j = 0; j < 8; ++j)
        Bu[cl + 16*j][kk] = src[16*j];
    }
    __syncthreads();
    short8v af[4], bfv[4];
    #pragma unroll
    for (int cf = 0; cf < 4; ++cf)
      af[cf] = *(const short8v*)&Au[row0w + cf*16 + lr][lg*8];
    #pragma unroll
    for (int df = 0; df < 4; ++df)
      bfv[df] = *(const short8v*)&Bu[col0w + df*16 + lr][lg*8];
    #pragma unroll
    for (int cf = 0; cf < 4; ++cf)
      #pragma unroll
      for (int df = 0; df < 4; ++df)
        acc[cf][df] = __builtin_amdgcn_mfma_f32_16x16x32_bf16(
                        af[cf], bfv[df], acc[cf][df], 0, 0, 0);
    __syncthreads();
  }
  const float g = gammas[gi];
  #pragma unroll
  for (int cf = 0; cf < 4; ++cf)
    #pragma unroll
    for (int df = 0; df < 4; ++df)
      #pragma unroll
      for (int r = 0; r < 4; ++r) {
        const int row = row0w + cf*16 + lg*4 + r;
        const int col = n0 + col0w + df*16 + lr;
        const size_t o = ((size_t)(b*CC_ + row))*HWn + col;
        fio[o] = g*acc[cf][df][r] + us2f(((const u16*)fb)[o]);
      }
}

// ---------------------------------------------------------------------------
// MFMA attH: eH[h][g] per (b,w). gl16 staging into [2][128][32].
// ---------------------------------------------------------------------------
__global__ __launch_bounds__(256)
void k_attHm(const bf16* __restrict__ qt, const bf16* __restrict__ kt,
             bf16* __restrict__ att)
{
  const int b = blockIdx.x >> 7, w = blockIdx.x & 127;
  __shared__ __align__(16) u16 Qs[2][128][32];
  __shared__ __align__(16) u16 Ks[2][128][32];
  const int tid = threadIdx.x;
  const int wid = tid >> 6, lane = tid & 63;
  const int lr = lane & 15, lg = lane >> 4;
  const int lrow = lane >> 2, lci = (lane & 3) * 8;
  const int h0w = (wid & 1) * 64, g0w = (wid >> 1) * 64;
  for (int ci = wid; ci < 16; ci += 4) {
    const int seg = ci >> 3, rq = (ci & 7) * 16;
    const int row = rq + lrow;
    const size_t gb = (((size_t)(b*HH + row))*WW + w)*64 + seg*32 + lci;
    gl16((const u16*)qt + gb, &Qs[seg][rq][0]);
    gl16((const u16*)kt + gb, &Ks[seg][rq][0]);
  }
  __syncthreads();
  f32x4 acc[4][4] = {};
  #pragma unroll
  for (int ks = 0; ks < 2; ++ks) {
    short8v af[4], bfv[4];
    #pragma unroll
    for (int hf = 0; hf < 4; ++hf)
      af[hf] = *(const short8v*)&Qs[ks][h0w + hf*16 + lr][lg*8];
    #pragma unroll
    for (int gf = 0; gf < 4; ++gf)
      bfv[gf] = *(const short8v*)&Ks[ks][g0w + gf*16 + lr][lg*8];
    #pragma unroll
    for (int hf = 0; hf < 4; ++hf)
      #pragma unroll
      for (int gf = 0; gf < 4; ++gf)
        acc[hf][gf] = __builtin_amdgcn_mfma_f32_16x16x32_bf16(
                        af[hf], bfv[gf], acc[hf][gf], 0, 0, 0);
  }
  #pragma unroll
  for (int hf = 0; hf < 4; ++hf)
    #pragma unroll
    for (int r = 0; r < 4; ++r) {
      const int h = h0w + hf*16 + lg*4 + r;
      u16* prow = (u16*)att + (((size_t)b*HH + h)*WW + w)*256 + g0w;
      #pragma unroll
      for (int gf = 0; gf < 4; ++gf)
        prow[gf*16 + lr] = f2us(acc[hf][gf][r]);
    }
}

// MFMA attW: eW[w][v] per (b,h). gl16 staging into [2][128][32].
__global__ __launch_bounds__(256)
void k_attWm(const bf16* __restrict__ qt, const bf16* __restrict__ kt,
             bf16* __restrict__ att)
{
  const int b = blockIdx.x >> 7, h = blockIdx.x & 127;
  __shared__ __align__(16) u16 Qs[2][128][32];
  __shared__ __align__(16) u16 Ks[2][128][32];
  const int tid = threadIdx.x;
  const int wid = tid >> 6, lane = tid & 63;
  const int lr = lane & 15, lg = lane >> 4;
  const int lrow = lane >> 2, lci = (lane & 3) * 8;
  const int w0w = (wid & 1) * 64, v0w = (wid >> 1) * 64;
  for (int ci = wid; ci < 16; ci += 4) {
    const int seg = ci >> 3, rq = (ci & 7) * 16;
    const int row = rq + lrow;
    const size_t gb = (((size_t)(b*HH + h))*WW + row)*64 + seg*32 + lci;
    gl16((const u16*)qt + gb, &Qs[seg][rq][0]);
    gl16((const u16*)kt + gb, &Ks[seg][rq][0]);
  }
  __syncthreads();
  f32x4 acc[4][4] = {};
  #pragma unroll
  for (int ks = 0; ks < 2; ++ks) {
    short8v af[4], bfv[4];
    #pragma unroll
    for (int wf = 0; wf < 4; ++wf)
      af[wf] = *(const short8v*)&Qs[ks][w0w + wf*16 + lr][lg*8];
    #pragma unroll
    for (int vf = 0; vf < 4; ++vf)
      bfv[vf] = *(const short8v*)&Ks[ks][v0w + vf*16 + lr][lg*8];
    #pragma unroll
    for (int wf = 0; wf < 4; ++wf)
      #pragma unroll
      for (int vf = 0; vf < 4; ++vf)
        acc[wf][vf] = __builtin_amdgcn_mfma_f32_16x16x32_bf16(
                        af[wf], bfv[vf], acc[wf][vf], 0, 0, 0);
  }
  #pragma unroll
  for (int wf = 0; wf < 4; ++wf)
    #pragma unroll
    for (int r = 0; r < 4; ++r) {
      const int wloc = w0w + wf*16 + lg*4 + r;
      u16* prow = (u16*)att + ((((size_t)b*HH + h)*WW + wloc)*256 + 128) + v0w;
      #pragma unroll
      for (int vf = 0; vf < 4; ++vf)
        prow[vf*16 + lr] = f2us(acc[wf][vf][r]);
    }
}

// softmax over 256 bf16 per pixel, in place. One wave per row.
__global__ __launch_bounds__(256)
void k_ccsm(bf16* __restrict__ att)
{
  const int row  = blockIdx.x * 4 + (threadIdx.x >> 6);
  const int lane = threadIdx.x & 63;
  u16* __restrict__ p = (u16*)att + (size_t)row * 256 + lane * 4;
  const ushort4 u = *(const ushort4*)p;
  float v0 = us2f(u.x), v1 = us2f(u.y), v2 = us2f(u.z), v3 = us2f(u.w);
  float m = fmaxf(fmaxf(v0, v1), fmaxf(v2, v3));
  #pragma unroll
  for (int o = 32; o; o >>= 1) m = fmaxf(m, __shfl_xor(m, o, 64));
  const float e0 = __expf(v0-m), e1 = __expf(v1-m), e2 = __expf(v2-m), e3 = __expf(v3-m);
  float s = e0 + e1 + e2 + e3;
  #pragma unroll
  for (int o = 32; o; o >>= 1) s += __shfl_xor(s, o, 64);
  const float inv = 1.f / s;
  st4((bf16*)p, e0*inv, e1*inv, e2*inv, e3*inv);
}

// ---------------------------------------------------------------------------
// MFMA outW: yt[w][c] = sum_v att[w][128+v] * V[v][c] per (b,h).
// ---------------------------------------------------------------------------
__global__ __launch_bounds__(256)
void k_outWm(const bf16* __restrict__ vt, const bf16* __restrict__ att,
             bf16* __restrict__ yt)
{
  const int b = blockIdx.y >> 7, h = blockIdx.y & 127;
  const int ch0 = blockIdx.x * 128;
  __shared__ u16 As[128][72];   // [w][v-chunk]
  __shared__ u16 Bs[128][72];   // [c][v-chunk] (transposed V)
  const int tid = threadIdx.x;
  const int wid = tid >> 6, lane = tid & 63;
  const int lr = lane & 15, lg = lane >> 4;
  const int w0w = (wid & 1) * 64, c0w = (wid >> 1) * 64;

  f32x4 acc[4][4] = {};

  for (int v0 = 0; v0 < 128; v0 += 64) {
    {
      const int row = tid >> 1, kq = (tid & 1) * 32;
      const u16* src = (const u16*)att + ((((size_t)b*HH + h)*WW + row)*256 + 128) + v0 + kq;
      #pragma unroll
      for (int j = 0; j < 4; ++j)
        *(uint4*)&As[row][kq + j*8] = *(const uint4*)(src + j*8);
    }
    {
      const int vv = tid & 63, cg0 = (tid >> 6) * 32;
      #pragma unroll
      for (int j2 = 0; j2 < 4; ++j2) {
        const int c8 = cg0 + j2*8;
        u16 t[8];
        *(uint4*)t = *(const uint4*)((const u16*)vt +
            (((size_t)(b*HH + h))*WW + (v0 + vv))*256 + ch0 + c8);
        #pragma unroll
        for (int jj = 0; jj < 8; ++jj) Bs[c8 + jj][vv] = t[jj];
      }
    }
    __syncthreads();
    #pragma unroll
    for (int ks = 0; ks < 2; ++ks) {
      short8v af[4], bfv[4];
      #pragma unroll
      for (int wf = 0; wf < 4; ++wf)
        af[wf] = *(const short8v*)&As[w0w + wf*16 + lr][ks*32 + lg*8];
      #pragma unroll
      for (int cf = 0; cf < 4; ++cf)
        bfv[cf] = *(const short8v*)&Bs[c0w + cf*16 + lr][ks*32 + lg*8];
      #pragma unroll
      for (int wf = 0; wf < 4; ++wf)
        #pragma unroll
        for (int cf = 0; cf < 4; ++cf)
          acc[wf][cf] = __builtin_amdgcn_mfma_f32_16x16x32_bf16(
                          af[wf], bfv[cf], acc[wf][cf], 0, 0, 0);
    }
    __syncthreads();
  }
  #pragma unroll
  for (int wf = 0; wf < 4; ++wf)
    #pragma unroll
    for (int r = 0; r < 4; ++r) {
      const int wpix = w0w + wf*16 + lg*4 + r;
      u16* drow = (u16*)yt + (((size_t)(b*HH + h))*WW + wpix)*256 + ch0 + c0w;
      #pragma unroll
      for (int cf = 0; cf < 4; ++cf)
        drow[cf*16 + lr] = f2us(acc[wf][cf][r]);
    }
}

// MFMA outH: xt[h][c] = yt[h][c] + sum_g att[h][g] * V[(g,w)][c] per (b,w).
__global__ __launch_bounds__(256)
void k_outHm(const bf16* __restrict__ vt, const bf16* __restrict__ att,
             const bf16* __restrict__ yt, bf16* __restrict__ xt)
{
  const int b = blockIdx.y >> 7, w = blockIdx.y & 127;
  const int ch0 = blockIdx.x * 128;
  __shared__ u16 As[128][72];   // [h][g-chunk]
  __shared__ u16 Bs[128][72];   // [c][g-chunk] (transposed V)
  const int tid = threadIdx.x;
  const int wid = tid >> 6, lane = tid & 63;
  const int lr = lane & 15, lg = lane >> 4;
  const int h0w = (wid & 1) * 64, c0w = (wid >> 1) * 64;

  f32x4 acc[4][4] = {};

  for (int g0 = 0; g0 < 128; g0 += 64) {
    {
      const int row = tid >> 1, kq = (tid & 1) * 32;
      const u16* src = (const u16*)att + (((size_t)b*HH + row)*WW + w)*256 + g0 + kq;
      #pragma unroll
      for (int j = 0; j < 4; ++j)
        *(uint4*)&As[row][kq + j*8] = *(const uint4*)(src + j*8);
    }
    {
      const int gg = tid & 63, cg0 = (tid >> 6) * 32;
      #pragma unroll
      for (int j2 = 0; j2 < 4; ++j2) {
        const int c8 = cg0 + j2*8;
        u16 t[8];
        *(uint4*)t = *(const uint4*)((const u16*)vt +
            (((size_t)(b*HH + (g0 + gg)))*WW + w)*256 + ch0 + c8);
        #pragma unroll
        for (int jj = 0; jj < 8; ++jj) Bs[c8 + jj][gg] = t[jj];
      }
    }
    __syncthreads();
    #pragma unroll
    for (int ks = 0; ks < 2; ++ks) {
      short8v af[4], bfv[4];
      #pragma unroll
      for (int hf = 0; hf < 4; ++hf)
        af[hf] = *(const short8v*)&As[h0w + hf*16 + lr][ks*32 + lg*8];
      #pragma unroll
      for (int cf = 0; cf < 4; ++cf)
        bfv[cf] = *(const short8v*)&Bs[c0w + cf*16 + lr][ks*32 + lg*8];
      #pragma unroll
      for (int hf = 0; hf < 4; ++hf)
        #pragma unroll
        for (int cf = 0; cf < 4; ++cf)
          acc[hf][cf] = __builtin_amdgcn_mfma_f32_16x16x32_bf16(
                          af[hf], bfv[cf], acc[hf][cf], 0, 0, 0);
    }
    __syncthreads();
  }
  #pragma unroll
  for (int hf = 0; hf < 4; ++hf)
    #pragma unroll
    for (int r = 0; r < 4; ++r) {
      const int hh = h0w + hf*16 + lg*4 + r;
      const size_t base = (((size_t)(b*HH + hh))*WW + w)*256 + ch0 + c0w;
      #pragma unroll
      for (int cf = 0; cf < 4; ++cf) {
        const size_t o = base + cf*16 + lr;
        ((u16*)xt)[o] = f2us(acc[hf][cf][r] + us2f(((const u16*)yt)[o]));
      }
    }
}

// scale + softmax over d, in place f32. rown holds raw sumsq (sqrt here).
__global__ __launch_bounds__(256)
void k_camsm(float* __restrict__ energy, const float* __restrict__ rown)
{
  const int row  = blockIdx.x * 4 + (threadIdx.x >> 6);
  const int lane = threadIdx.x & 63;
  const int b = row >> 8;
  float* __restrict__ p = energy + (size_t)row * 256 + lane * 4;
  const float rc = sqrtf(rown[row]) + 1e-10f;
  float4 rd = *(const float4*)(rown + b*256 + lane*4);
  rd.x = sqrtf(rd.x) + 1e-10f; rd.y = sqrtf(rd.y) + 1e-10f;
  rd.z = sqrtf(rd.z) + 1e-10f; rd.w = sqrtf(rd.w) + 1e-10f;
  float4 v = *(const float4*)p;
  v.x /= (rc*rd.x); v.y /= (rc*rd.y); v.z /= (rc*rd.z); v.w /= (rc*rd.w);
  float m = fmaxf(fmaxf(v.x, v.y), fmaxf(v.z, v.w));
  #pragma unroll
  for (int o = 32; o; o >>= 1) m = fmaxf(m, __shfl_xor(m, o, 64));
  const float e0 = __expf(v.x-m), e1 = __expf(v.y-m), e2 = __expf(v.z-m), e3 = __expf(v.w-m);
  float s = e0 + e1 + e2 + e3;
  #pragma unroll
  for (int o = 32; o; o >>= 1) s += __shfl_xor(s, o, 64);
  const float inv = 1.f / s;
  *(float4*)p = make_float4(e0*inv, e1*inv, e2*inv, e3*inv);
}

// ---------------------------------------------------------------------------
extern "C" void kernel_launch(void* const* d_in, const int* in_sizes, int n_in,
                              void* d_out, int out_size, void* d_ws, size_t ws_size,
                              hipStream_t stream)
{
  const float* x     = (const float*)d_in[0];
  const float* w_[5]  = {(const float*)d_in[1],(const float*)d_in[2],(const float*)d_in[3],(const float*)d_in[4],(const float*)d_in[5]};
  const float* s_[5]  = {(const float*)d_in[6],(const float*)d_in[7],(const float*)d_in[8],(const float*)d_in[9],(const float*)d_in[10]};
  const float* bi_[5] = {(const float*)d_in[11],(const float*)d_in[12],(const float*)d_in[13],(const float*)d_in[14],(const float*)d_in[15]};
  const float* wq = (const float*)d_in[16];
  const float* bq = (const float*)d_in[17];
  const float* wk = (const float*)d_in[18];
  const float* bk = (const float*)d_in[19];
  const float* wv = (const float*)d_in[20];
  const float* bv = (const float*)d_in[21];
  const float* gam = (const float*)d_in[22];
  float* out = (float*)d_out;   // f32, 5 slots of SZ

  // Workspace layout (~155 MB, proven envelope; CC buffers disjoint).
  // stats(128f) | energy(262144f) | rown(1024f) are contiguous -> one memset.
  char* wsc = (char*)d_ws;
  bf16*  Tc16 = (bf16*)wsc;
  bf16*  qt   = (bf16*)wsc;
  bf16*  kt   = qt + SZ/4;
  bf16*  vt   = qt + SZ/2;
  bf16*  attb = qt + SZ/2 + SZ;
  bf16*  xt   = attb + SZ;
  bf16*  yt   = xt + SZ;
  bf16*  wtb  = yt + SZ;
  bf16*  wtq  = wtb;
  bf16*  wtk  = wtb + 16384;
  bf16*  wtv  = wtb + 32768;
  float* stats  = (float*)(wtb + 16*65536);
  float* energy = stats + 128;
  float* rown   = energy + 262144;
  float* slot4 = out + 4*SZ;
  bf16*  fbA   = attb;  // branches 0-3: bf16 GN output (CAM input)
  bf16*  fb16  = vt;    // branch 4: bf16 CC output copy (CAM input)

  const int dil_[5] = {1, 6, 12, 18, 1};

  // ---- branches 0-3: fused ASPP + CAM (stats/rown fused into conv/apply) --
  k_xpose<<<512,256,0,stream>>>(x, xt);
  for (int i = 0; i < 4; ++i) {
    hipMemsetAsync(stats, 0, (size_t)(128 + 262144 + 1024)*sizeof(float), stream);
    const int taps = (i == 0) ? 1 : 9;
    k_wt<<<taps*256,256,0,stream>>>(w_[i], wtb, taps);
    if (i == 0) k_convm<1,bf16,false,true,false><<<dim3(4,512),256,0,stream>>>(xt, wtb, nullptr, Tc16, 1, 256, stats);
    else        k_convm<3,bf16,false,true,false><<<dim3(4,512),256,0,stream>>>(xt, wtb, nullptr, Tc16, dil_[i], 256, stats);
    k_gn_applyb<<<16384,256,0,stream>>>(Tc16, stats, s_[i], bi_[i], fbA, rown);
    k_energym<<<dim3(4,32,4),256,0,stream>>>(fbA, energy);
    k_camsm<<<256,256,0,stream>>>(energy, rown);
    k_camoutm<<<dim3(128,4),512,0,stream>>>(energy, fbA, out + (size_t)i*SZ, gam, i);
  }

  // ---- branch 4 ASPP: conv (fused stats) -> fused GN+transpose -> xt ----
  {
    hipMemsetAsync(stats, 0, 128*sizeof(float), stream);
    k_wt<<<9*256,256,0,stream>>>(w_[4], wtb, 9);
    k_convm<3,bf16,false,true,false><<<dim3(4,512),256,0,stream>>>(xt, wtb, nullptr, Tc16, 1, 256, stats);
    k_xpose_gn<<<512,256,0,stream>>>(Tc16, stats, s_[4], bi_[4], xt);
  }

  // ---- criss-cross attention x2, fully c-last; all GEMMs via MFMA.
  //      q/k convs carry the fused per-pixel L2-norm (QKNORM). ----
  k_wt<<<64,256,0,stream>>>(wq, wtq, 1);
  k_wt<<<64,256,0,stream>>>(wk, wtk, 1);
  k_wt<<<256,256,0,stream>>>(wv, wtv, 1);
  for (int it = 0; it < 2; ++it) {
    k_convm<1,bf16,true,false,true><<<dim3(1,512),256,0,stream>>>(xt, wtq, bq, qt, 1, 64, nullptr);
    k_convm<1,bf16,true,false,true><<<dim3(1,512),256,0,stream>>>(xt, wtk, bk, kt, 1, 64, nullptr);
    k_convm<1,bf16,true,false,false><<<dim3(4,512),256,0,stream>>>(xt, wtv, bv, vt, 1, 256, nullptr);
    k_attHm<<<512,256,0,stream>>>(qt, kt, attb);
    k_attWm<<<512,256,0,stream>>>(qt, kt, attb);
    k_ccsm<<<16384,256,0,stream>>>(attb);
    k_outWm<<<dim3(2,512),256,0,stream>>>(vt, attb, yt);
    k_outHm<<<dim3(2,512),256,0,stream>>>(vt, attb, yt, xt);
  }

  // ---- CAM on branch 4: xt -> bf16 NCHW copy with fused row-sumsq ----
  {
    hipMemsetAsync(energy, 0, (size_t)(262144 + 1024)*sizeof(float), stream);
    k_xposeb_b<<<512,256,0,stream>>>(xt, fb16, rown);
    k_energym<<<dim3(4,32,4),256,0,stream>>>(fb16, energy);
    k_camsm<<<256,256,0,stream>>>(energy, rown);
    k_camoutm<<<dim3(128,4),512,0,stream>>>(energy, fb16, slot4, gam, 4);
  }
}

// Round 28
// 1287.399 us; speedup vs baseline: 1.0563x; 1.0194x over previous
//
#include <hip/hip_runtime.h>
#include <hip/hip_bf16.h>

typedef __hip_bfloat16 bf16;
typedef unsigned short u16;
typedef __attribute__((ext_vector_type(8))) short short8v;  // 8 bf16 (4 VGPR)
typedef __attribute__((ext_vector_type(4))) float f32x4;

#define BB   4
#define CC_  256
#define HH   128
#define WW   128
#define HWn  16384
#define SZ   ((size_t)16777216)   // BB*CC_*HWn elements per slot

__device__ __forceinline__ float b2f(bf16 v){ return __bfloat162float(v); }
__device__ __forceinline__ bf16  f2b(float v){ return __float2bfloat16(v); }
__device__ __forceinline__ float us2f(u16 u){
  union { unsigned int i; float f; } x; x.i = ((unsigned int)u) << 16; return x.f;
}
__device__ __forceinline__ u16 f2us(float v){
  bf16 h = f2b(v); u16 u; __builtin_memcpy(&u, &h, 2); return u;
}
__device__ __forceinline__ void st4(float* p, float a, float b, float c, float d){
  *(float4*)p = make_float4(a,b,c,d);
}
__device__ __forceinline__ void st4(bf16* p, float a, float b, float c, float d){
  bf16 o[4] = { f2b(a), f2b(b), f2b(c), f2b(d) };
  *(uint2*)p = *(uint2*)o;
}
__device__ __forceinline__ void store1(float* p, float v){ *p = v; }
__device__ __forceinline__ void store1(bf16* p, float v){ *p = f2b(v); }

// Direct global->LDS 16B async load (per-lane global src, wave-uniform LDS
// base; lane i lands at base + i*16B).
typedef __attribute__((address_space(1))) const unsigned int u32g;
typedef __attribute__((address_space(3))) unsigned int u32l;
__device__ __forceinline__ void gl16(const void* g, void* l)
{
  u32g* gp = (u32g*)(unsigned long long)(size_t)g;
  u32l* lp = (u32l*)(unsigned int)(size_t)l;
  __builtin_amdgcn_global_load_lds(gp, lp, 16, 0, 0);
}

// ---------------------------------------------------------------------------
// Transpose [B,256,H,W] f32 -> [B,H,W,256] bf16. One block per (b,h).
// ---------------------------------------------------------------------------
__global__ __launch_bounds__(256)
void k_xpose(const float* __restrict__ x, bf16* __restrict__ xt)
{
  const int b = blockIdx.x >> 7, h = blockIdx.x & 127;
  __shared__ u16 L[64][132];
  const int tid = threadIdx.x;
  for (int c0 = 0; c0 < 256; c0 += 64) {
    for (int idx = tid; idx < 2048; idx += 256) {
      const int c = idx >> 5, w4 = (idx & 31) * 4;
      const float4 v = *(const float4*)&x[(((size_t)(b*CC_ + c0 + c))*HH + h)*WW + w4];
      L[c][w4]   = f2us(v.x); L[c][w4+1] = f2us(v.y);
      L[c][w4+2] = f2us(v.z); L[c][w4+3] = f2us(v.w);
    }
    __syncthreads();
    for (int idx = tid; idx < 1024; idx += 256) {
      const int w = idx >> 3, cg = (idx & 7) * 8;
      u16 tmp[8];
      #pragma unroll
      for (int j = 0; j < 8; ++j) tmp[j] = L[cg + j][w];
      *(uint4*)&xt[(((size_t)(b*HH + h))*WW + w)*256 + c0 + cg] = *(uint4*)tmp;
    }
    __syncthreads();
  }
}

// Fused GN-apply + transpose (branch 4): Tc16 [B,C,H,W] bf16 + stats ->
// xt [B,H,W,256] bf16.
__global__ __launch_bounds__(256)
void k_xpose_gn(const bf16* __restrict__ t, const float* __restrict__ stats,
                const float* __restrict__ sc, const float* __restrict__ bi,
                bf16* __restrict__ xt)
{
  const int b = blockIdx.x >> 7, h = blockIdx.x & 127;
  __shared__ u16 L[64][132];
  const int tid = threadIdx.x;
  const float cnt = 16.f * 16384.f;
  for (int c0 = 0; c0 < 256; c0 += 64) {
    for (int idx = tid; idx < 1024; idx += 256) {
      const int c = idx >> 4, w8 = (idx & 15) * 8;
      const int cg = c0 + c;
      const int bg = b*16 + (cg >> 4);
      const float mu  = stats[bg*2] / cnt;
      const float var = stats[bg*2+1] / cnt - mu * mu;
      const float a   = rsqrtf(var + 1e-5f) * sc[cg];
      const float bb  = bi[cg] - mu * a;
      u16 t8[8];
      *(uint4*)t8 = *(const uint4*)((const u16*)t + (((size_t)(b*CC_ + cg))*HH + h)*WW + w8);
      #pragma unroll
      for (int j = 0; j < 8; ++j) t8[j] = f2us(fmaxf(us2f(t8[j])*a + bb, 0.f));
      #pragma unroll
      for (int j = 0; j < 8; ++j) L[c][w8 + j] = t8[j];
    }
    __syncthreads();
    for (int idx = tid; idx < 1024; idx += 256) {
      const int w = idx >> 3, cg = (idx & 7) * 8;
      u16 tmp[8];
      #pragma unroll
      for (int j = 0; j < 8; ++j) tmp[j] = L[cg + j][w];
      *(uint4*)&xt[(((size_t)(b*HH + h))*WW + w)*256 + c0 + cg] = *(uint4*)tmp;
    }
    __syncthreads();
  }
}

// Inverse for branch-4 CC output: [B,H,W,256] bf16 -> [B,256,H,W] bf16,
// with fused CAM row-sumsq (32-lane-group reduce + 1 atomic per (b,c)).
__global__ __launch_bounds__(256)
void k_xposeb_b(const bf16* __restrict__ xt, bf16* __restrict__ fb,
                float* __restrict__ rownsq)
{
  const int b = blockIdx.x >> 7, h = blockIdx.x & 127;
  __shared__ u16 L[64][132];
  const int tid = threadIdx.x;
  for (int c0 = 0; c0 < 256; c0 += 64) {
    for (int idx = tid; idx < 1024; idx += 256) {
      const int w = idx >> 3, cg = (idx & 7) * 8;
      u16 t[8];
      *(uint4*)t = *(const uint4*)((const u16*)xt + (((size_t)(b*HH + h))*WW + w)*256 + c0 + cg);
      #pragma unroll
      for (int j = 0; j < 8; ++j) L[cg + j][w] = t[j];
    }
    __syncthreads();
    for (int idx = tid; idx < 2048; idx += 256) {
      const int c = idx >> 5, w4 = (idx & 31) * 4;
      u16 q[4] = { L[c][w4], L[c][w4+1], L[c][w4+2], L[c][w4+3] };
      *(uint2*)((u16*)fb + (((size_t)(b*CC_ + c0 + c))*HH + h)*WW + w4) = *(uint2*)q;
      float sq = 0.f;
      #pragma unroll
      for (int j = 0; j < 4; ++j) { const float v = us2f(q[j]); sq = fmaf(v, v, sq); }
      #pragma unroll
      for (int o = 16; o > 0; o >>= 1) sq += __shfl_xor(sq, o, 64);
      if ((tid & 31) == 0) atomicAdd(&rownsq[b*256 + c0 + c], sq);
    }
    __syncthreads();
  }
}

// Weights [CO,CI,taps] f32 -> wt [taps,CO,CI] bf16.
__global__ __launch_bounds__(256)
void k_wt(const float* __restrict__ w, bf16* __restrict__ wt, int taps)
{
  const int i = blockIdx.x * 256 + threadIdx.x;
  const int tap = i >> 16, r = i & 65535;
  const int co = r >> 8, ci = r & 255;
  if (tap < taps) wt[i] = f2b(w[(co*256 + ci)*taps + tap]);
}

// ---------------------------------------------------------------------------
// MFMA conv with global_load_lds staging (r21 proven). LDS linear [rows][32].
// STATS: fused GroupNorm stats (r23 proven).
// QKNORM (TRANS, CO==64, grid.x==1): fused per-pixel L2-normalize over the
// 64 output channels (replaces k_qknorm_t).
// ---------------------------------------------------------------------------
template<int KHW, typename DT, bool TRANS, bool STATS, bool QKNORM>
__global__ __launch_bounds__(256)
void k_convm(const bf16* __restrict__ xt, const bf16* __restrict__ wt,
             const float* __restrict__ bias, DT* __restrict__ dst, int dil, int CO,
             float* __restrict__ stats)
{
  const int b   = blockIdx.y >> 7;
  const int h   = blockIdx.y & 127;
  const int co0 = blockIdx.x * 64;
  const int tid = threadIdx.x;
  const int wid = tid >> 6;
  const int lane = tid & 63;
  const int lr = lane & 15;
  const int lg = lane >> 4;
  const int lrow = lane >> 2;        // row within 16-row chunk
  const int lci  = (lane & 3) * 8;   // 16B slot (8 u16) within row

  __shared__ __align__(16) u16 Asld[KHW*64][32];
  __shared__ __align__(16) u16 Bsld[164][32];

  // Pre-zero the constant pad rows of B (0..17 and 146..163).
  for (int i = tid; i < 36*32; i += 256) {
    int r = i >> 5; r = (r < 18) ? r : (128 + r);
    Bsld[r][i & 31] = 0;
  }

  f32x4 acc[4][2] = {};

  for (int kh = 0; kh < KHW; ++kh) {
    const int hh = h + (kh - (KHW >> 1)) * dil;
    if (hh < 0 || hh >= HH) continue;
    const bf16* __restrict__ brow = xt + ((size_t)(b*HH + hh))*WW*256;
    for (int kc = 0; kc < 256; kc += 32) {
      for (int ch = wid; ch < KHW*4; ch += 4) {
        const int row = ch*16 + lrow;
        const int tap = row >> 6, cc = row & 63;
        gl16(wt + ((size_t)(kh*KHW + tap))*CO*256 + (co0 + cc)*256 + kc + lci,
             &Asld[ch*16][0]);
      }
      for (int ch = wid; ch < 8; ch += 4) {
        const int wpos = ch*16 + lrow;
        gl16(brow + (size_t)wpos*256 + kc + lci, &Bsld[18 + ch*16][0]);
      }
      __syncthreads();
      #pragma unroll
      for (int kw = 0; kw < KHW; ++kw) {
        const int pbase = 18 + (kw - (KHW >> 1)) * dil;
        short8v af[4], bfr[2];
        #pragma unroll
        for (int cf = 0; cf < 4; ++cf)
          af[cf] = *(const short8v*)&Asld[kw*64 + cf*16 + lr][lg*8];
        #pragma unroll
        for (int wf = 0; wf < 2; ++wf)
          bfr[wf] = *(const short8v*)&Bsld[pbase + wid*32 + wf*16 + lr][lg*8];
        #pragma unroll
        for (int cf = 0; cf < 4; ++cf)
          #pragma unroll
          for (int wf = 0; wf < 2; ++wf)
            acc[cf][wf] = __builtin_amdgcn_mfma_f32_16x16x32_bf16(
                            af[cf], bfr[wf], acc[cf][wf], 0, 0, 0);
      }
      __syncthreads();
    }
  }
  if constexpr (TRANS) {
    if constexpr (QKNORM) {
      // CO==64, co0==0. Fused per-pixel L2-norm over 64 channels.
      #pragma unroll
      for (int wf = 0; wf < 2; ++wf) {
        float vr[16];
        float sq = 0.f;
        #pragma unroll
        for (int cf = 0; cf < 4; ++cf)
          #pragma unroll
          for (int r = 0; r < 4; ++r) {
            const float v = us2f(f2us(acc[cf][wf][r] + bias[cf*16 + lg*4 + r]));
            vr[cf*4 + r] = v;
            sq = fmaf(v, v, sq);
          }
        sq += __shfl_xor(sq, 16, 64);
        sq += __shfl_xor(sq, 32, 64);
        const float rn = 1.f / (sqrtf(sq) + 1e-10f);
        const int wpix = wid*32 + wf*16 + lr;
        bf16* dr = (bf16*)dst + (((size_t)(b*HH + h))*WW + wpix)*CO + lg*4;
        #pragma unroll
        for (int cf = 0; cf < 4; ++cf) {
          bf16 o4[4];
          #pragma unroll
          for (int r = 0; r < 4; ++r) o4[r] = f2b(vr[cf*4 + r] * rn);
          *(uint2*)(dr + cf*16) = *(uint2*)o4;
        }
      }
    } else {
      #pragma unroll
      for (int cf = 0; cf < 4; ++cf) {
        float bb[4];
        #pragma unroll
        for (int r = 0; r < 4; ++r)
          bb[r] = bias ? bias[co0 + cf*16 + lg*4 + r] : 0.f;
        #pragma unroll
        for (int wf = 0; wf < 2; ++wf) {
          const int wpix = wid*32 + wf*16 + lr;
          bf16* dr = (bf16*)dst + (((size_t)(b*HH + h))*WW + wpix)*CO + co0 + cf*16 + lg*4;
          bf16 o4[4];
          #pragma unroll
          for (int r = 0; r < 4; ++r) o4[r] = f2b(acc[cf][wf][r] + bb[r]);
          *(uint2*)dr = *(uint2*)o4;
        }
      }
    }
  } else {
    float s0[4] = {0.f,0.f,0.f,0.f}, s1[4] = {0.f,0.f,0.f,0.f};
    #pragma unroll
    for (int cf = 0; cf < 4; ++cf) {
      #pragma unroll
      for (int r = 0; r < 4; ++r) {
        const int co = co0 + cf*16 + lg*4 + r;
        const float bb = bias ? bias[co] : 0.f;
        DT* drow = dst + (((size_t)(b*CO + co))*HH + h)*WW;
        #pragma unroll
        for (int wf = 0; wf < 2; ++wf) {
          const float v = acc[cf][wf][r] + bb;
          store1(drow + wid*32 + wf*16 + lr, v);
          if constexpr (STATS) {
            const float vr = us2f(f2us(v));   // rounded value, as stored
            s0[cf] += vr;
            s1[cf] = fmaf(vr, vr, s1[cf]);
          }
        }
      }
    }
    if constexpr (STATS) {
      #pragma unroll
      for (int cf = 0; cf < 4; ++cf)
        #pragma unroll
        for (int o = 32; o > 0; o >>= 1) {
          s0[cf] += __shfl_down(s0[cf], o, 64);
          s1[cf] += __shfl_down(s1[cf], o, 64);
        }
      __shared__ float sred[4][4][2];
      if (lane == 0) {
        #pragma unroll
        for (int cf = 0; cf < 4; ++cf) { sred[wid][cf][0] = s0[cf]; sred[wid][cf][1] = s1[cf]; }
      }
      __syncthreads();
      if (tid < 8) {
        const int cf = tid >> 1, j = tid & 1;
        const float t = sred[0][cf][j] + sred[1][cf][j] + sred[2][cf][j] + sred[3][cf][j];
        atomicAdd(&stats[(b*16 + (co0 >> 4) + cf)*2 + j], t);
      }
    }
  }
}

// GroupNorm apply -> bf16 (branches 0-3), fused CAM row-sumsq.
__global__ __launch_bounds__(256)
void k_gn_applyb(const bf16* __restrict__ t, const float* __restrict__ stats,
                 const float* __restrict__ sc, const float* __restrict__ bi,
                 bf16* __restrict__ dst, float* __restrict__ rownsq)
{
  const size_t e = ((size_t)blockIdx.x * 256 + threadIdx.x) * 4;
  const int c  = (int)((e >> 14) & 255);
  const int bg = (int)(e >> 22) * 16 + (c >> 4);
  const float cnt = 16.f * 16384.f;
  const float mu  = stats[bg*2] / cnt;
  const float var = stats[bg*2+1] / cnt - mu * mu;
  const float rs  = rsqrtf(var + 1e-5f);
  const float a   = rs * sc[c];
  const float bb  = bi[c] - mu * a;
  const ushort4 u = *(const ushort4*)((const u16*)t + e);
  u16 q[4] = { f2us(fmaxf(us2f(u.x)*a+bb,0.f)), f2us(fmaxf(us2f(u.y)*a+bb,0.f)),
               f2us(fmaxf(us2f(u.z)*a+bb,0.f)), f2us(fmaxf(us2f(u.w)*a+bb,0.f)) };
  *(uint2*)((u16*)dst + e) = *(uint2*)q;
  float sq = 0.f;
  #pragma unroll
  for (int j = 0; j < 4; ++j) { const float w = us2f(q[j]); sq = fmaf(w, w, sq); }
  #pragma unroll
  for (int o = 32; o > 0; o >>= 1) sq += __shfl_down(sq, o, 64);
  __shared__ float sh[4];
  const int wid = threadIdx.x >> 6, lane = threadIdx.x & 63;
  if (lane == 0) sh[wid] = sq;
  __syncthreads();
  if (threadIdx.x == 0) atomicAdd(&rownsq[blockIdx.x >> 4], sh[0]+sh[1]+sh[2]+sh[3]);
}

// ---------------------------------------------------------------------------
// MFMA energy: E[b] += F.F^T (bf16 copy of slot). Tile 128x128, split-K 32
// (k-chunk 512). gl16 staging into segmented LDS [2][128][32]. Full 4 tiles.
// ---------------------------------------------------------------------------
__global__ __launch_bounds__(256)
void k_energym(const bf16* __restrict__ fb, float* __restrict__ energy)
{
  const int b  = blockIdx.z;
  const int c0 = (blockIdx.x >> 1) * 128, d0 = (blockIdx.x & 1) * 128;
  const int k0 = blockIdx.y * 512;
  __shared__ __align__(16) u16 Au[2][128][32];
  __shared__ __align__(16) u16 Bu[2][128][32];
  const int tid = threadIdx.x;
  const int wid = tid >> 6, lane = tid & 63;
  const int lr = lane & 15, lg = lane >> 4;
  const int lrow = lane >> 2, lci = (lane & 3) * 8;
  const int row0w = (wid & 1) * 64, col0w = (wid >> 1) * 64;
  const u16* __restrict__ fbb = (const u16*)fb + (size_t)b * CC_ * HWn;

  f32x4 acc[4][4] = {};

  for (int kc = 0; kc < 512; kc += 64) {
    for (int ci = wid; ci < 16; ci += 4) {
      const int seg = ci >> 3, rq = (ci & 7) * 16;
      const int m = rq + lrow;
      gl16(fbb + (size_t)(c0 + m)*HWn + k0 + kc + seg*32 + lci, &Au[seg][rq][0]);
      gl16(fbb + (size_t)(d0 + m)*HWn + k0 + kc + seg*32 + lci, &Bu[seg][rq][0]);
    }
    __syncthreads();
    #pragma unroll
    for (int ks = 0; ks < 2; ++ks) {
      short8v af[4], bfv[4];
      #pragma unroll
      for (int cf = 0; cf < 4; ++cf)
        af[cf] = *(const short8v*)&Au[ks][row0w + cf*16 + lr][lg*8];
      #pragma unroll
      for (int df = 0; df < 4; ++df)
        bfv[df] = *(const short8v*)&Bu[ks][col0w + df*16 + lr][lg*8];
      #pragma unroll
      for (int cf = 0; cf < 4; ++cf)
        #pragma unroll
        for (int df = 0; df < 4; ++df)
          acc[cf][df] = __builtin_amdgcn_mfma_f32_16x16x32_bf16(
                          af[cf], bfv[df], acc[cf][df], 0, 0, 0);
    }
    __syncthreads();
  }
  #pragma unroll
  for (int cf = 0; cf < 4; ++cf)
    #pragma unroll
    for (int df = 0; df < 4; ++df)
      #pragma unroll
      for (int r = 0; r < 4; ++r) {
        const int row = c0 + row0w + cf*16 + lg*4 + r;
        const int col = d0 + col0w + df*16 + lr;
        atomicAdd(&energy[((size_t)(b*CC_ + row))*CC_ + col], acc[cf][df][r]);
      }
}

// ---------------------------------------------------------------------------
// MFMA camout: out = gamma*(att@f) + f. A from bf16 softmax output (catt16,
// written by k_camsm — identical rounded values to the old f32->f2us chain),
// B and residual from bf16 copy. B staging: r23-proven pattern.
// ---------------------------------------------------------------------------
__global__ __launch_bounds__(512)
void k_camoutm(const bf16* __restrict__ catt16, const bf16* __restrict__ fb,
               float* __restrict__ fio, const float* __restrict__ gammas, int gi)
{
  const int b  = blockIdx.y;
  const int n0 = blockIdx.x * 128;
  __shared__ u16 Au[256][40];
  __shared__ u16 Bu[128][40];
  const int tid = threadIdx.x;
  const int wid = tid >> 6, lane = tid & 63;
  const int lr = lane & 15, lg = lane >> 4;
  const int row0w = (wid & 3) * 64, col0w = (wid >> 2) * 64;

  f32x4 acc[4][4] = {};

  for (int k0 = 0; k0 < 256; k0 += 32) {
    {
      const int m = tid >> 1, kh = (tid & 1) * 16;
      const u16* src = (const u16*)catt16 + ((size_t)(b*CC_ + m))*CC_ + k0 + kh;
      *(uint4*)&Au[m][kh]   = *(const uint4*)(src);
      *(uint4*)&Au[m][kh+8] = *(const uint4*)(src + 8);
    }
    {
      const int kk = tid >> 4, cl = tid & 15;
      const u16* src = (const u16*)fb + ((size_t)(b*CC_ + k0 + kk))*HWn + n0 + cl;
      #pragma unroll
      for (int j = 0; j < 8; ++j)
        Bu[cl + 16*j][kk] = src[16*j];
    }
    __syncthreads();
    short8v af[4], bfv[4];
    #pragma unroll
    for (int cf = 0; cf < 4; ++cf)
      af[cf] = *(const short8v*)&Au[row0w + cf*16 + lr][lg*8];
    #pragma unroll
    for (int df = 0; df < 4; ++df)
      bfv[df] = *(const short8v*)&Bu[col0w + df*16 + lr][lg*8];
    #pragma unroll
    for (int cf = 0; cf < 4; ++cf)
      #pragma unroll
      for (int df = 0; df < 4; ++df)
        acc[cf][df] = __builtin_amdgcn_mfma_f32_16x16x32_bf16(
                        af[cf], bfv[df], acc[cf][df], 0, 0, 0);
    __syncthreads();
  }
  const float g = gammas[gi];
  #pragma unroll
  for (int cf = 0; cf < 4; ++cf)
    #pragma unroll
    for (int df = 0; df < 4; ++df)
      #pragma unroll
      for (int r = 0; r < 4; ++r) {
        const int row = row0w + cf*16 + lg*4 + r;
        const int col = n0 + col0w + df*16 + lr;
        const size_t o = ((size_t)(b*CC_ + row))*HWn + col;
        fio[o] = g*acc[cf][df][r] + us2f(((const u16*)fb)[o]);
      }
}

// ---------------------------------------------------------------------------
// MFMA attH: eH[h][g] per (b,w). gl16 staging into [2][128][32].
// ---------------------------------------------------------------------------
__global__ __launch_bounds__(256)
void k_attHm(const bf16* __restrict__ qt, const bf16* __restrict__ kt,
             bf16* __restrict__ att)
{
  const int b = blockIdx.x >> 7, w = blockIdx.x & 127;
  __shared__ __align__(16) u16 Qs[2][128][32];
  __shared__ __align__(16) u16 Ks[2][128][32];
  const int tid = threadIdx.x;
  const int wid = tid >> 6, lane = tid & 63;
  const int lr = lane & 15, lg = lane >> 4;
  const int lrow = lane >> 2, lci = (lane & 3) * 8;
  const int h0w = (wid & 1) * 64, g0w = (wid >> 1) * 64;
  for (int ci = wid; ci < 16; ci += 4) {
    const int seg = ci >> 3, rq = (ci & 7) * 16;
    const int row = rq + lrow;
    const size_t gb = (((size_t)(b*HH + row))*WW + w)*64 + seg*32 + lci;
    gl16((const u16*)qt + gb, &Qs[seg][rq][0]);
    gl16((const u16*)kt + gb, &Ks[seg][rq][0]);
  }
  __syncthreads();
  f32x4 acc[4][4] = {};
  #pragma unroll
  for (int ks = 0; ks < 2; ++ks) {
    short8v af[4], bfv[4];
    #pragma unroll
    for (int hf = 0; hf < 4; ++hf)
      af[hf] = *(const short8v*)&Qs[ks][h0w + hf*16 + lr][lg*8];
    #pragma unroll
    for (int gf = 0; gf < 4; ++gf)
      bfv[gf] = *(const short8v*)&Ks[ks][g0w + gf*16 + lr][lg*8];
    #pragma unroll
    for (int hf = 0; hf < 4; ++hf)
      #pragma unroll
      for (int gf = 0; gf < 4; ++gf)
        acc[hf][gf] = __builtin_amdgcn_mfma_f32_16x16x32_bf16(
                        af[hf], bfv[gf], acc[hf][gf], 0, 0, 0);
  }
  #pragma unroll
  for (int hf = 0; hf < 4; ++hf)
    #pragma unroll
    for (int r = 0; r < 4; ++r) {
      const int h = h0w + hf*16 + lg*4 + r;
      u16* prow = (u16*)att + (((size_t)b*HH + h)*WW + w)*256 + g0w;
      #pragma unroll
      for (int gf = 0; gf < 4; ++gf)
        prow[gf*16 + lr] = f2us(acc[hf][gf][r]);
    }
}

// MFMA attW: eW[w][v] per (b,h). gl16 staging into [2][128][32].
__global__ __launch_bounds__(256)
void k_attWm(const bf16* __restrict__ qt, const bf16* __restrict__ kt,
             bf16* __restrict__ att)
{
  const int b = blockIdx.x >> 7, h = blockIdx.x & 127;
  __shared__ __align__(16) u16 Qs[2][128][32];
  __shared__ __align__(16) u16 Ks[2][128][32];
  const int tid = threadIdx.x;
  const int wid = tid >> 6, lane = tid & 63;
  const int lr = lane & 15, lg = lane >> 4;
  const int lrow = lane >> 2, lci = (lane & 3) * 8;
  const int w0w = (wid & 1) * 64, v0w = (wid >> 1) * 64;
  for (int ci = wid; ci < 16; ci += 4) {
    const int seg = ci >> 3, rq = (ci & 7) * 16;
    const int row = rq + lrow;
    const size_t gb = (((size_t)(b*HH + h))*WW + row)*64 + seg*32 + lci;
    gl16((const u16*)qt + gb, &Qs[seg][rq][0]);
    gl16((const u16*)kt + gb, &Ks[seg][rq][0]);
  }
  __syncthreads();
  f32x4 acc[4][4] = {};
  #pragma unroll
  for (int ks = 0; ks < 2; ++ks) {
    short8v af[4], bfv[4];
    #pragma unroll
    for (int wf = 0; wf < 4; ++wf)
      af[wf] = *(const short8v*)&Qs[ks][w0w + wf*16 + lr][lg*8];
    #pragma unroll
    for (int vf = 0; vf < 4; ++vf)
      bfv[vf] = *(const short8v*)&Ks[ks][v0w + vf*16 + lr][lg*8];
    #pragma unroll
    for (int wf = 0; wf < 4; ++wf)
      #pragma unroll
      for (int vf = 0; vf < 4; ++vf)
        acc[wf][vf] = __builtin_amdgcn_mfma_f32_16x16x32_bf16(
                        af[wf], bfv[vf], acc[wf][vf], 0, 0, 0);
  }
  #pragma unroll
  for (int wf = 0; wf < 4; ++wf)
    #pragma unroll
    for (int r = 0; r < 4; ++r) {
      const int wloc = w0w + wf*16 + lg*4 + r;
      u16* prow = (u16*)att + ((((size_t)b*HH + h)*WW + wloc)*256 + 128) + v0w;
      #pragma unroll
      for (int vf = 0; vf < 4; ++vf)
        prow[vf*16 + lr] = f2us(acc[wf][vf][r]);
    }
}

// softmax over 256 bf16 per pixel, in place. One wave per row.
__global__ __launch_bounds__(256)
void k_ccsm(bf16* __restrict__ att)
{
  const int row  = blockIdx.x * 4 + (threadIdx.x >> 6);
  const int lane = threadIdx.x & 63;
  u16* __restrict__ p = (u16*)att + (size_t)row * 256 + lane * 4;
  const ushort4 u = *(const ushort4*)p;
  float v0 = us2f(u.x), v1 = us2f(u.y), v2 = us2f(u.z), v3 = us2f(u.w);
  float m = fmaxf(fmaxf(v0, v1), fmaxf(v2, v3));
  #pragma unroll
  for (int o = 32; o; o >>= 1) m = fmaxf(m, __shfl_xor(m, o, 64));
  const float e0 = __expf(v0-m), e1 = __expf(v1-m), e2 = __expf(v2-m), e3 = __expf(v3-m);
  float s = e0 + e1 + e2 + e3;
  #pragma unroll
  for (int o = 32; o; o >>= 1) s += __shfl_xor(s, o, 64);
  const float inv = 1.f / s;
  st4((bf16*)p, e0*inv, e1*inv, e2*inv, e3*inv);
}

// ---------------------------------------------------------------------------
// MFMA outW: yt[w][c] = sum_v att[w][128+v] * V[v][c] per (b,h).
// ---------------------------------------------------------------------------
__global__ __launch_bounds__(256)
void k_outWm(const bf16* __restrict__ vt, const bf16* __restrict__ att,
             bf16* __restrict__ yt)
{
  const int b = blockIdx.y >> 7, h = blockIdx.y & 127;
  const int ch0 = blockIdx.x * 128;
  __shared__ u16 As[128][72];   // [w][v-chunk]
  __shared__ u16 Bs[128][72];   // [c][v-chunk] (transposed V)
  const int tid = threadIdx.x;
  const int wid = tid >> 6, lane = tid & 63;
  const int lr = lane & 15, lg = lane >> 4;
  const int w0w = (wid & 1) * 64, c0w = (wid >> 1) * 64;

  f32x4 acc[4][4] = {};

  for (int v0 = 0; v0 < 128; v0 += 64) {
    {
      const int row = tid >> 1, kq = (tid & 1) * 32;
      const u16* src = (const u16*)att + ((((size_t)b*HH + h)*WW + row)*256 + 128) + v0 + kq;
      #pragma unroll
      for (int j = 0; j < 4; ++j)
        *(uint4*)&As[row][kq + j*8] = *(const uint4*)(src + j*8);
    }
    {
      const int vv = tid & 63, cg0 = (tid >> 6) * 32;
      #pragma unroll
      for (int j2 = 0; j2 < 4; ++j2) {
        const int c8 = cg0 + j2*8;
        u16 t[8];
        *(uint4*)t = *(const uint4*)((const u16*)vt +
            (((size_t)(b*HH + h))*WW + (v0 + vv))*256 + ch0 + c8);
        #pragma unroll
        for (int jj = 0; jj < 8; ++jj) Bs[c8 + jj][vv] = t[jj];
      }
    }
    __syncthreads();
    #pragma unroll
    for (int ks = 0; ks < 2; ++ks) {
      short8v af[4], bfv[4];
      #pragma unroll
      for (int wf = 0; wf < 4; ++wf)
        af[wf] = *(const short8v*)&As[w0w + wf*16 + lr][ks*32 + lg*8];
      #pragma unroll
      for (int cf = 0; cf < 4; ++cf)
        bfv[cf] = *(const short8v*)&Bs[c0w + cf*16 + lr][ks*32 + lg*8];
      #pragma unroll
      for (int wf = 0; wf < 4; ++wf)
        #pragma unroll
        for (int cf = 0; cf < 4; ++cf)
          acc[wf][cf] = __builtin_amdgcn_mfma_f32_16x16x32_bf16(
                          af[wf], bfv[cf], acc[wf][cf], 0, 0, 0);
    }
    __syncthreads();
  }
  #pragma unroll
  for (int wf = 0; wf < 4; ++wf)
    #pragma unroll
    for (int r = 0; r < 4; ++r) {
      const int wpix = w0w + wf*16 + lg*4 + r;
      u16* drow = (u16*)yt + (((size_t)(b*HH + h))*WW + wpix)*256 + ch0 + c0w;
      #pragma unroll
      for (int cf = 0; cf < 4; ++cf)
        drow[cf*16 + lr] = f2us(acc[wf][cf][r]);
    }
}

// MFMA outH: xt[h][c] = yt[h][c] + sum_g att[h][g] * V[(g,w)][c] per (b,w).
__global__ __launch_bounds__(256)
void k_outHm(const bf16* __restrict__ vt, const bf16* __restrict__ att,
             const bf16* __restrict__ yt, bf16* __restrict__ xt)
{
  const int b = blockIdx.y >> 7, w = blockIdx.y & 127;
  const int ch0 = blockIdx.x * 128;
  __shared__ u16 As[128][72];   // [h][g-chunk]
  __shared__ u16 Bs[128][72];   // [c][g-chunk] (transposed V)
  const int tid = threadIdx.x;
  const int wid = tid >> 6, lane = tid & 63;
  const int lr = lane & 15, lg = lane >> 4;
  const int h0w = (wid & 1) * 64, c0w = (wid >> 1) * 64;

  f32x4 acc[4][4] = {};

  for (int g0 = 0; g0 < 128; g0 += 64) {
    {
      const int row = tid >> 1, kq = (tid & 1) * 32;
      const u16* src = (const u16*)att + (((size_t)b*HH + row)*WW + w)*256 + g0 + kq;
      #pragma unroll
      for (int j = 0; j < 4; ++j)
        *(uint4*)&As[row][kq + j*8] = *(const uint4*)(src + j*8);
    }
    {
      const int gg = tid & 63, cg0 = (tid >> 6) * 32;
      #pragma unroll
      for (int j2 = 0; j2 < 4; ++j2) {
        const int c8 = cg0 + j2*8;
        u16 t[8];
        *(uint4*)t = *(const uint4*)((const u16*)vt +
            (((size_t)(b*HH + (g0 + gg)))*WW + w)*256 + ch0 + c8);
        #pragma unroll
        for (int jj = 0; jj < 8; ++jj) Bs[c8 + jj][gg] = t[jj];
      }
    }
    __syncthreads();
    #pragma unroll
    for (int ks = 0; ks < 2; ++ks) {
      short8v af[4], bfv[4];
      #pragma unroll
      for (int hf = 0; hf < 4; ++hf)
        af[hf] = *(const short8v*)&As[h0w + hf*16 + lr][ks*32 + lg*8];
      #pragma unroll
      for (int cf = 0; cf < 4; ++cf)
        bfv[cf] = *(const short8v*)&Bs[c0w + cf*16 + lr][ks*32 + lg*8];
      #pragma unroll
      for (int hf = 0; hf < 4; ++hf)
        #pragma unroll
        for (int cf = 0; cf < 4; ++cf)
          acc[hf][cf] = __builtin_amdgcn_mfma_f32_16x16x32_bf16(
                          af[hf], bfv[cf], acc[hf][cf], 0, 0, 0);
    }
    __syncthreads();
  }
  #pragma unroll
  for (int hf = 0; hf < 4; ++hf)
    #pragma unroll
    for (int r = 0; r < 4; ++r) {
      const int hh = h0w + hf*16 + lg*4 + r;
      const size_t base = (((size_t)(b*HH + hh))*WW + w)*256 + ch0 + c0w;
      #pragma unroll
      for (int cf = 0; cf < 4; ++cf) {
        const size_t o = base + cf*16 + lr;
        ((u16*)xt)[o] = f2us(acc[hf][cf][r] + us2f(((const u16*)yt)[o]));
      }
    }
}

// scale + softmax over d; reads f32 energy, writes bf16 catt16 (the only
// consumer is camoutm's MFMA A-operand; values identical to the old
// f32->f2us chain in camoutm). rown holds raw sumsq (sqrt here).
__global__ __launch_bounds__(256)
void k_camsm(const float* __restrict__ energy, const float* __restrict__ rown,
             bf16* __restrict__ catt16)
{
  const int row  = blockIdx.x * 4 + (threadIdx.x >> 6);
  const int lane = threadIdx.x & 63;
  const int b = row >> 8;
  const float* __restrict__ p = energy + (size_t)row * 256 + lane * 4;
  const float rc = sqrtf(rown[row]) + 1e-10f;
  float4 rd = *(const float4*)(rown + b*256 + lane*4);
  rd.x = sqrtf(rd.x) + 1e-10f; rd.y = sqrtf(rd.y) + 1e-10f;
  rd.z = sqrtf(rd.z) + 1e-10f; rd.w = sqrtf(rd.w) + 1e-10f;
  float4 v = *(const float4*)p;
  v.x /= (rc*rd.x); v.y /= (rc*rd.y); v.z /= (rc*rd.z); v.w /= (rc*rd.w);
  float m = fmaxf(fmaxf(v.x, v.y), fmaxf(v.z, v.w));
  #pragma unroll
  for (int o = 32; o; o >>= 1) m = fmaxf(m, __shfl_xor(m, o, 64));
  const float e0 = __expf(v.x-m), e1 = __expf(v.y-m), e2 = __expf(v.z-m), e3 = __expf(v.w-m);
  float s = e0 + e1 + e2 + e3;
  #pragma unroll
  for (int o = 32; o; o >>= 1) s += __shfl_xor(s, o, 64);
  const float inv = 1.f / s;
  st4(catt16 + (size_t)row * 256 + lane * 4, e0*inv, e1*inv, e2*inv, e3*inv);
}

// ---------------------------------------------------------------------------
extern "C" void kernel_launch(void* const* d_in, const int* in_sizes, int n_in,
                              void* d_out, int out_size, void* d_ws, size_t ws_size,
                              hipStream_t stream)
{
  const float* x     = (const float*)d_in[0];
  const float* w_[5]  = {(const float*)d_in[1],(const float*)d_in[2],(const float*)d_in[3],(const float*)d_in[4],(const float*)d_in[5]};
  const float* s_[5]  = {(const float*)d_in[6],(const float*)d_in[7],(const float*)d_in[8],(const float*)d_in[9],(const float*)d_in[10]};
  const float* bi_[5] = {(const float*)d_in[11],(const float*)d_in[12],(const float*)d_in[13],(const float*)d_in[14],(const float*)d_in[15]};
  const float* wq = (const float*)d_in[16];
  const float* bq = (const float*)d_in[17];
  const float* wk = (const float*)d_in[18];
  const float* bk = (const float*)d_in[19];
  const float* wv = (const float*)d_in[20];
  const float* bv = (const float*)d_in[21];
  const float* gam = (const float*)d_in[22];
  float* out = (float*)d_out;   // f32, 5 slots of SZ

  // Workspace layout (~154.6 MB; CC buffers disjoint).
  // stats(128f) | energy(262144f) | rown(1024f) | catt16(512KB bf16).
  char* wsc = (char*)d_ws;
  bf16*  Tc16 = (bf16*)wsc;
  bf16*  qt   = (bf16*)wsc;
  bf16*  kt   = qt + SZ/4;
  bf16*  vt   = qt + SZ/2;
  bf16*  attb = qt + SZ/2 + SZ;
  bf16*  xt   = attb + SZ;
  bf16*  yt   = xt + SZ;
  bf16*  wtb  = yt + SZ;
  bf16*  wtq  = wtb;
  bf16*  wtk  = wtb + 16384;
  bf16*  wtv  = wtb + 32768;
  float* stats  = (float*)(wtb + 16*65536);
  float* energy = stats + 128;
  float* rown   = energy + 262144;
  bf16*  catt16 = (bf16*)(rown + 1024);
  float* slot4 = out + 4*SZ;
  bf16*  fbA   = attb;  // branches 0-3: bf16 GN output (CAM input)
  bf16*  fb16  = vt;    // branch 4: bf16 CC output copy (CAM input)

  const int dil_[5] = {1, 6, 12, 18, 1};

  // ---- branches 0-3: fused ASPP + CAM (stats/rown fused into conv/apply) --
  k_xpose<<<512,256,0,stream>>>(x, xt);
  for (int i = 0; i < 4; ++i) {
    hipMemsetAsync(stats, 0, (size_t)(128 + 262144 + 1024)*sizeof(float), stream);
    const int taps = (i == 0) ? 1 : 9;
    k_wt<<<taps*256,256,0,stream>>>(w_[i], wtb, taps);
    if (i == 0) k_convm<1,bf16,false,true,false><<<dim3(4,512),256,0,stream>>>(xt, wtb, nullptr, Tc16, 1, 256, stats);
    else        k_convm<3,bf16,false,true,false><<<dim3(4,512),256,0,stream>>>(xt, wtb, nullptr, Tc16, dil_[i], 256, stats);
    k_gn_applyb<<<16384,256,0,stream>>>(Tc16, stats, s_[i], bi_[i], fbA, rown);
    k_energym<<<dim3(4,32,4),256,0,stream>>>(fbA, energy);
    k_camsm<<<256,256,0,stream>>>(energy, rown, catt16);
    k_camoutm<<<dim3(128,4),512,0,stream>>>(catt16, fbA, out + (size_t)i*SZ, gam, i);
  }

  // ---- branch 4 ASPP: conv (fused stats) -> fused GN+transpose -> xt ----
  {
    hipMemsetAsync(stats, 0, 128*sizeof(float), stream);
    k_wt<<<9*256,256,0,stream>>>(w_[4], wtb, 9);
    k_convm<3,bf16,false,true,false><<<dim3(4,512),256,0,stream>>>(xt, wtb, nullptr, Tc16, 1, 256, stats);
    k_xpose_gn<<<512,256,0,stream>>>(Tc16, stats, s_[4], bi_[4], xt);
  }

  // ---- criss-cross attention x2, fully c-last; all GEMMs via MFMA.
  //      q/k convs carry the fused per-pixel L2-norm (QKNORM). ----
  k_wt<<<64,256,0,stream>>>(wq, wtq, 1);
  k_wt<<<64,256,0,stream>>>(wk, wtk, 1);
  k_wt<<<256,256,0,stream>>>(wv, wtv, 1);
  for (int it = 0; it < 2; ++it) {
    k_convm<1,bf16,true,false,true><<<dim3(1,512),256,0,stream>>>(xt, wtq, bq, qt, 1, 64, nullptr);
    k_convm<1,bf16,true,false,true><<<dim3(1,512),256,0,stream>>>(xt, wtk, bk, kt, 1, 64, nullptr);
    k_convm<1,bf16,true,false,false><<<dim3(4,512),256,0,stream>>>(xt, wtv, bv, vt, 1, 256, nullptr);
    k_attHm<<<512,256,0,stream>>>(qt, kt, attb);
    k_attWm<<<512,256,0,stream>>>(qt, kt, attb);
    k_ccsm<<<16384,256,0,stream>>>(attb);
    k_outWm<<<dim3(2,512),256,0,stream>>>(vt, attb, yt);
    k_outHm<<<dim3(2,512),256,0,stream>>>(vt, attb, yt, xt);
  }

  // ---- CAM on branch 4: xt -> bf16 NCHW copy with fused row-sumsq ----
  {
    hipMemsetAsync(energy, 0, (size_t)(262144 + 1024)*sizeof(float), stream);
    k_xposeb_b<<<512,256,0,stream>>>(xt, fb16, rown);
    k_energym<<<dim3(4,32,4),256,0,stream>>>(fb16, energy);
    k_camsm<<<256,256,0,stream>>>(energy, rown, catt16);
    k_camoutm<<<dim3(128,4),512,0,stream>>>(catt16, fb16, slot4, gam, 4);
  }
}